// Round 1
// baseline (1029.812 us; speedup 1.0000x reference)
//
#include <hip/hip_runtime.h>

#define NN 100000
#define NE 1600000
#define DD 128
#define HH 32

// ---- workspace layout (bytes) ----
#define OFF_P        0UL          // N*32 f32 = 12,800,000
#define OFF_T        12800000UL   // N*32 f32
#define OFF_CSR      25600000UL   // E i32 = 6,400,000
#define OFF_ROWOFF   32000000UL   // (N+1) i32
#define OFF_CURSOR   32400128UL   // N i32
#define OFF_DEG      32800128UL   // N i32            (memset region start)
#define OFF_STATS    33200128UL   // 4*128 f32        (memset region: 402048 B)
#define OFF_BSUM     33202176UL   // 391 i32 (pad 1792)
#define OFF_BOFF     33203968UL   // 391 i32 (pad 1792)
#define OFF_W1T      33205760UL   // 4096 f32
#define OFF_W2T      33222144UL   // 4096 f32
#define OFF_MT       33238528UL   // 3072 f32
#define OFF_C        33250816UL   // 96 f32 (pad 512)
#define OFF_W3T      33251328UL   // 4096 f32
#define NBLK_NODES   391          // ceil(100000/256)

// ---------- CSR build ----------
__global__ void k_hist(const int* __restrict__ ei, int* __restrict__ deg) {
    int e = blockIdx.x * 256 + threadIdx.x;
    if (e < NE) atomicAdd(&deg[ei[NE + e]], 1);
}

__global__ void k_scanA(const int* __restrict__ deg, int* __restrict__ bsum) {
    __shared__ int s[256];
    int t = threadIdx.x, i = blockIdx.x * 256 + t;
    s[t] = (i < NN) ? deg[i] : 0;
    __syncthreads();
    for (int off = 128; off > 0; off >>= 1) {
        if (t < off) s[t] += s[t + off];
        __syncthreads();
    }
    if (t == 0) bsum[blockIdx.x] = s[0];
}

__global__ void k_scanB(const int* __restrict__ bsum, int* __restrict__ boff) {
    __shared__ int s[512];
    int t = threadIdx.x;
    int v = (t < NBLK_NODES) ? bsum[t] : 0;
    s[t] = v;
    __syncthreads();
    for (int off = 1; off < 512; off <<= 1) {
        int x = (t >= off) ? s[t - off] : 0;
        __syncthreads();
        s[t] += x;
        __syncthreads();
    }
    if (t < NBLK_NODES) boff[t] = s[t] - v;  // exclusive
}

__global__ void k_scanC(const int* __restrict__ deg, const int* __restrict__ boff,
                        int* __restrict__ row_off, int* __restrict__ cursor) {
    __shared__ int s[256];
    int t = threadIdx.x, i = blockIdx.x * 256 + t;
    int v = (i < NN) ? deg[i] : 0;
    s[t] = v;
    __syncthreads();
    for (int off = 1; off < 256; off <<= 1) {
        int x = (t >= off) ? s[t - off] : 0;
        __syncthreads();
        s[t] += x;
        __syncthreads();
    }
    int excl = s[t] - v;
    int base = boff[blockIdx.x];
    if (i < NN) {
        int r = base + excl;
        row_off[i] = r;
        cursor[i]  = r;
        if (i == NN - 1) row_off[NN] = r + v;
    }
}

__global__ void k_fill(const int* __restrict__ ei, int* __restrict__ cursor,
                       int* __restrict__ csr) {
    int e = blockIdx.x * 256 + threadIdx.x;
    if (e < NE) {
        int d = ei[NE + e];
        int pos = atomicAdd(&cursor[d], 1);
        csr[pos] = ei[e];
    }
}

// ---------- weight prep: transposes + fused chain matrices ----------
// MT[l][k][i] = sum_m W1[l+1][i][m] * W3[l][m][k]   (l=0..2), input-major
// C[l][i]    = sum_m W1[l+1][i][m] * b3[l][m]
// W1T[k][j]  = W1[0][j][k]   (128x32)
// W2T[l][k][j] = W2[l][j][k] (32x32 per layer)
// W3T[k][j]  = W3[3][j][k]   (32x128)
__global__ void k_prep(const float* __restrict__ W1, const float* __restrict__ W2,
                       const float* __restrict__ W3, const float* __restrict__ b3,
                       float* __restrict__ W1T, float* __restrict__ W2T,
                       float* __restrict__ MT, float* __restrict__ C,
                       float* __restrict__ W3T) {
    int t = threadIdx.x;          // 1024 threads
    int i = t >> 5, j = t & 31;   // i: 0..31, j: 0..31
    for (int l = 0; l < 3; l++) {
        const float* w1r = W1 + (l + 1) * HH * DD + i * DD;
        const float* w3c = W3 + l * DD * HH + j;
        float m = 0.f;
        for (int k = 0; k < DD; k++) m += w1r[k] * w3c[k * HH];
        MT[l * 1024 + j * 32 + i] = m;
    }
    if (t < 96) {
        int l = t >> 5, ii = t & 31;
        const float* w1r = W1 + (l + 1) * HH * DD + ii * DD;
        const float* bb = b3 + l * DD;
        float c = 0.f;
        for (int k = 0; k < DD; k++) c += w1r[k] * bb[k];
        C[l * 32 + ii] = c;
    }
    for (int idx = t; idx < 4096; idx += 1024) {
        int jj = idx >> 7, kk = idx & 127;          // jj:0..31, kk:0..127
        W1T[kk * 32 + jj] = W1[jj * 128 + kk];
    }
    for (int l = 0; l < 4; l++)
        W2T[l * 1024 + j * 32 + i] = W2[l * 1024 + t];   // t = i*32+j
    for (int idx = t; idx < 4096; idx += 1024) {
        int jj = idx >> 5, kk = idx & 31;           // jj:0..127, kk:0..31
        W3T[kk * 128 + jj] = W3[3 * 4096 + jj * 32 + kk];
    }
}

// ---------- P = X @ W1[0]^T  (layer 0 only) ----------
__global__ void __launch_bounds__(256) k_P(const float* __restrict__ X,
                                           const float* __restrict__ W1T,
                                           float* __restrict__ P) {
    int n = blockIdx.x * 256 + threadIdx.x;
    if (n >= NN) return;
    const float4* Xr = (const float4*)(X + (size_t)n * DD);
    const float4* W = (const float4*)W1T;    // idx: k*8 + j4
    float4 acc[8];
#pragma unroll
    for (int j = 0; j < 8; j++) acc[j] = make_float4(0.f, 0.f, 0.f, 0.f);
#pragma unroll 4
    for (int k4 = 0; k4 < 32; k4++) {
        float4 x = Xr[k4];
#pragma unroll
        for (int j = 0; j < 8; j++) {
            float4 w0 = W[(4 * k4 + 0) * 8 + j];
            float4 w1 = W[(4 * k4 + 1) * 8 + j];
            float4 w2 = W[(4 * k4 + 2) * 8 + j];
            float4 w3 = W[(4 * k4 + 3) * 8 + j];
            acc[j].x += x.x * w0.x + x.y * w1.x + x.z * w2.x + x.w * w3.x;
            acc[j].y += x.x * w0.y + x.y * w1.y + x.z * w2.y + x.w * w3.y;
            acc[j].z += x.x * w0.z + x.y * w1.z + x.z * w2.z + x.w * w3.z;
            acc[j].w += x.x * w0.w + x.y * w1.w + x.z * w2.w + x.w * w3.w;
        }
    }
    float4* Pr = (float4*)(P + (size_t)n * HH);
#pragma unroll
    for (int j = 0; j < 8; j++) Pr[j] = acc[j];
}

// ---------- aggregate + t1 = (1+eps)P_n + sum_nb P + b1; BN1 stats ----------
// 8 lanes per node, lane owns 4 columns (one float4). grid = 3125 blocks x 256.
__global__ void __launch_bounds__(256) k_A(const float4* __restrict__ P4,
                                           const int* __restrict__ csr,
                                           const int* __restrict__ row_off,
                                           const float* __restrict__ eps,
                                           const float* __restrict__ b1, int l,
                                           float4* __restrict__ T4,
                                           float* __restrict__ gs) {
    __shared__ float ls[64];
    int t = threadIdx.x;
    if (t < 64) ls[t] = 0.f;
    __syncthreads();
    int g = t >> 3, i = t & 7;
    int n = blockIdx.x * 32 + g;
    float e1 = 1.f + eps[l];
    int e0 = row_off[n], eend = row_off[n + 1];
    float4 p = P4[(size_t)n * 8 + i];
    float4 acc;
    acc.x = e1 * p.x; acc.y = e1 * p.y; acc.z = e1 * p.z; acc.w = e1 * p.w;
    for (int e = e0; e < eend; e++) {
        int s = csr[e];
        float4 q = P4[(size_t)s * 8 + i];
        acc.x += q.x; acc.y += q.y; acc.z += q.z; acc.w += q.w;
    }
    float4 bb = ((const float4*)(b1 + l * 32))[i];
    acc.x += bb.x; acc.y += bb.y; acc.z += bb.z; acc.w += bb.w;
    T4[(size_t)n * 8 + i] = acc;
    atomicAdd(&ls[4 * i + 0], acc.x);
    atomicAdd(&ls[4 * i + 1], acc.y);
    atomicAdd(&ls[4 * i + 2], acc.z);
    atomicAdd(&ls[4 * i + 3], acc.w);
    atomicAdd(&ls[32 + 4 * i + 0], acc.x * acc.x);
    atomicAdd(&ls[32 + 4 * i + 1], acc.y * acc.y);
    atomicAdd(&ls[32 + 4 * i + 2], acc.z * acc.z);
    atomicAdd(&ls[32 + 4 * i + 3], acc.w * acc.w);
    __syncthreads();
    if (t < 64) atomicAdd(&gs[t], ls[t]);
}

// ---------- t2 = relu(bn1(t1)) @ W2^T + b2 (in-place on T); BN2 stats ----------
__global__ void __launch_bounds__(256) k_D(float* __restrict__ T,
                                           const float* __restrict__ W2T,
                                           const float* __restrict__ b2,
                                           const float* __restrict__ g1,
                                           const float* __restrict__ bt1, int l,
                                           float* __restrict__ gs) {
    __shared__ float sc[32], sh[32], ls[64];
    int t = threadIdx.x;
    if (t < 32) {
        float m = gs[t] * (1.f / NN);
        float var = gs[32 + t] * (1.f / NN) - m * m;
        float s = g1[l * 32 + t] * rsqrtf(var + 1e-5f);
        sc[t] = s; sh[t] = bt1[l * 32 + t] - m * s;
    } else if (t < 96) {
        ls[t - 32] = 0.f;
    }
    __syncthreads();
    int n = blockIdx.x * 256 + t;
    float4 acc[8];
    if (n < NN) {
        float4* Tr = (float4*)(T + (size_t)n * 32);
        float a1[32];
#pragma unroll
        for (int k4 = 0; k4 < 8; k4++) {
            float4 x = Tr[k4];
            a1[4 * k4 + 0] = fmaxf(x.x * sc[4 * k4 + 0] + sh[4 * k4 + 0], 0.f);
            a1[4 * k4 + 1] = fmaxf(x.y * sc[4 * k4 + 1] + sh[4 * k4 + 1], 0.f);
            a1[4 * k4 + 2] = fmaxf(x.z * sc[4 * k4 + 2] + sh[4 * k4 + 2], 0.f);
            a1[4 * k4 + 3] = fmaxf(x.w * sc[4 * k4 + 3] + sh[4 * k4 + 3], 0.f);
        }
        const float4* Wt = (const float4*)(W2T + l * 1024);
        const float4* b24 = (const float4*)(b2 + l * 32);
#pragma unroll
        for (int j = 0; j < 8; j++) acc[j] = b24[j];
#pragma unroll
        for (int k = 0; k < 32; k++) {
            float a = a1[k];
#pragma unroll
            for (int j = 0; j < 8; j++) {
                float4 w = Wt[k * 8 + j];
                acc[j].x += a * w.x; acc[j].y += a * w.y;
                acc[j].z += a * w.z; acc[j].w += a * w.w;
            }
        }
#pragma unroll
        for (int j = 0; j < 8; j++) Tr[j] = acc[j];
    } else {
#pragma unroll
        for (int j = 0; j < 8; j++) acc[j] = make_float4(0.f, 0.f, 0.f, 0.f);
    }
    // wave-level stats reduction (all lanes participate; inactive contribute 0)
#pragma unroll
    for (int j = 0; j < 8; j++) {
        float vx = acc[j].x, vy = acc[j].y, vz = acc[j].z, vw = acc[j].w;
        float qx = vx * vx, qy = vy * vy, qz = vz * vz, qw = vw * vw;
#pragma unroll
        for (int off = 1; off < 64; off <<= 1) {
            vx += __shfl_xor(vx, off); vy += __shfl_xor(vy, off);
            vz += __shfl_xor(vz, off); vw += __shfl_xor(vw, off);
            qx += __shfl_xor(qx, off); qy += __shfl_xor(qy, off);
            qz += __shfl_xor(qz, off); qw += __shfl_xor(qw, off);
        }
        if ((t & 63) == 0) {
            atomicAdd(&ls[4 * j + 0], vx); atomicAdd(&ls[4 * j + 1], vy);
            atomicAdd(&ls[4 * j + 2], vz); atomicAdd(&ls[4 * j + 3], vw);
            atomicAdd(&ls[32 + 4 * j + 0], qx); atomicAdd(&ls[32 + 4 * j + 1], qy);
            atomicAdd(&ls[32 + 4 * j + 2], qz); atomicAdd(&ls[32 + 4 * j + 3], qw);
        }
    }
    __syncthreads();
    if (t < 64) atomicAdd(&gs[64 + t], ls[t]);
}

// ---------- a2 = relu(bn2(t2)); l<3: P_next = M a2 + c ; l==3: out = W3 a2 + b3 ----------
__global__ void __launch_bounds__(256) k_F(const float* __restrict__ T,
                                           const float* __restrict__ g2,
                                           const float* __restrict__ bt2, int l,
                                           const float* __restrict__ gs,
                                           const float* __restrict__ MT,
                                           const float* __restrict__ C,
                                           const float* __restrict__ W3T,
                                           const float* __restrict__ b3,
                                           float* __restrict__ P,
                                           float* __restrict__ out) {
    __shared__ float sc[32], sh[32];
    int t = threadIdx.x;
    if (t < 32) {
        float m = gs[64 + t] * (1.f / NN);
        float var = gs[96 + t] * (1.f / NN) - m * m;
        float s = g2[l * 32 + t] * rsqrtf(var + 1e-5f);
        sc[t] = s; sh[t] = bt2[l * 32 + t] - m * s;
    }
    __syncthreads();
    int n = blockIdx.x * 256 + t;
    if (n >= NN) return;
    float a2[32];
    const float4* Tr = (const float4*)(T + (size_t)n * 32);
#pragma unroll
    for (int k4 = 0; k4 < 8; k4++) {
        float4 x = Tr[k4];
        a2[4 * k4 + 0] = fmaxf(x.x * sc[4 * k4 + 0] + sh[4 * k4 + 0], 0.f);
        a2[4 * k4 + 1] = fmaxf(x.y * sc[4 * k4 + 1] + sh[4 * k4 + 1], 0.f);
        a2[4 * k4 + 2] = fmaxf(x.z * sc[4 * k4 + 2] + sh[4 * k4 + 2], 0.f);
        a2[4 * k4 + 3] = fmaxf(x.w * sc[4 * k4 + 3] + sh[4 * k4 + 3], 0.f);
    }
    if (l < 3) {
        const float4* Mt = (const float4*)(MT + l * 1024);
        const float4* C4 = (const float4*)(C + l * 32);
        float4 acc[8];
#pragma unroll
        for (int j = 0; j < 8; j++) acc[j] = C4[j];
#pragma unroll
        for (int k = 0; k < 32; k++) {
            float a = a2[k];
#pragma unroll
            for (int j = 0; j < 8; j++) {
                float4 w = Mt[k * 8 + j];
                acc[j].x += a * w.x; acc[j].y += a * w.y;
                acc[j].z += a * w.z; acc[j].w += a * w.w;
            }
        }
        float4* Pr = (float4*)(P + (size_t)n * 32);
#pragma unroll
        for (int j = 0; j < 8; j++) Pr[j] = acc[j];
    } else {
        const float4* Wt = (const float4*)W3T;           // idx: k*32 + j4
        const float4* b34 = (const float4*)(b3 + 3 * 128);
        float4* Or = (float4*)(out + (size_t)n * 128);
#pragma unroll 4
        for (int j4 = 0; j4 < 32; j4++) {
            float4 acc = b34[j4];
#pragma unroll
            for (int k = 0; k < 32; k++) {
                float4 w = Wt[k * 32 + j4];
                float a = a2[k];
                acc.x += a * w.x; acc.y += a * w.y;
                acc.z += a * w.z; acc.w += a * w.w;
            }
            Or[j4] = acc;
        }
    }
}

extern "C" void kernel_launch(void* const* d_in, const int* in_sizes, int n_in,
                              void* d_out, int out_size, void* d_ws, size_t ws_size,
                              hipStream_t stream) {
    const float* X   = (const float*)d_in[0];
    const int*   EI  = (const int*)d_in[1];
    const float* eps = (const float*)d_in[2];
    const float* W1  = (const float*)d_in[3];
    const float* b1  = (const float*)d_in[4];
    const float* g1  = (const float*)d_in[5];
    const float* bt1 = (const float*)d_in[6];
    const float* W2  = (const float*)d_in[7];
    const float* b2  = (const float*)d_in[8];
    const float* g2  = (const float*)d_in[9];
    const float* bt2 = (const float*)d_in[10];
    const float* W3  = (const float*)d_in[11];
    const float* b3  = (const float*)d_in[12];

    char* ws = (char*)d_ws;
    float* P       = (float*)(ws + OFF_P);
    float* T       = (float*)(ws + OFF_T);
    int*   csr     = (int*)(ws + OFF_CSR);
    int*   row_off = (int*)(ws + OFF_ROWOFF);
    int*   cursor  = (int*)(ws + OFF_CURSOR);
    int*   deg     = (int*)(ws + OFF_DEG);
    float* stats   = (float*)(ws + OFF_STATS);
    int*   bsum    = (int*)(ws + OFF_BSUM);
    int*   boff    = (int*)(ws + OFF_BOFF);
    float* W1T     = (float*)(ws + OFF_W1T);
    float* W2T     = (float*)(ws + OFF_W2T);
    float* MT      = (float*)(ws + OFF_MT);
    float* C       = (float*)(ws + OFF_C);
    float* W3T     = (float*)(ws + OFF_W3T);

    // zero deg + stats (contiguous region)
    hipMemsetAsync(ws + OFF_DEG, 0, 402048, stream);

    k_hist<<<NE / 256, 256, 0, stream>>>(EI, deg);
    k_prep<<<1, 1024, 0, stream>>>(W1, W2, W3, b3, W1T, W2T, MT, C, W3T);
    k_scanA<<<NBLK_NODES, 256, 0, stream>>>(deg, bsum);
    k_scanB<<<1, 512, 0, stream>>>(bsum, boff);
    k_scanC<<<NBLK_NODES, 256, 0, stream>>>(deg, boff, row_off, cursor);
    k_fill<<<NE / 256, 256, 0, stream>>>(EI, cursor, csr);
    k_P<<<NBLK_NODES, 256, 0, stream>>>(X, W1T, P);

    for (int l = 0; l < 4; l++) {
        float* gs = stats + l * 128;
        k_A<<<NN / 32, 256, 0, stream>>>((const float4*)P, csr, row_off, eps, b1, l,
                                         (float4*)T, gs);
        k_D<<<NBLK_NODES, 256, 0, stream>>>(T, W2T, b2, g1, bt1, l, gs);
        k_F<<<NBLK_NODES, 256, 0, stream>>>(T, g2, bt2, l, gs, MT, C, W3T, b3, P,
                                            (float*)d_out);
    }
}

// Round 2
// 605.753 us; speedup vs baseline: 1.7001x; 1.7001x over previous
//
#include <hip/hip_runtime.h>

#define NN 100000
#define NE 1600000
#define DD 128
#define HH 32
#define NB 196        // dst buckets of 512 nodes
#define SB 256        // scatter blocks
#define EPB 6250      // edges per scatter block (SB*EPB == NE)
#define BCAP 12288    // bucket capacity for LDS stage (mean 8192, sd ~90)

// ---- workspace layout (bytes) ----
#define OFF_P        0UL          // N*32 f32 = 12,800,000
#define OFF_T        12800000UL   // N*32 f32
#define OFF_PK       25600000UL   // E i32 packed (src<<9|local) -> later aliased as csr
#define OFF_ROWOFF   32000000UL   // (N+1) i32 (pad to 400128)
#define OFF_COUNTS   32400128UL   // NB*SB i32 = 200704
#define OFF_POFS     32600832UL   // NB*SB i32
#define OFF_BTOT     32801536UL   // 196 i32 (pad 1024)
#define OFF_BBASE    32802560UL   // 197 i32 (pad 1024)
#define OFF_STATS    32803584UL   // 4*1024 f32 = 16384  (memset region)
#define OFF_W1T      32819968UL   // 4096 f32
#define OFF_W2T      32836352UL   // 4096 f32
#define OFF_MT       32852736UL   // 3072 f32
#define OFF_C        32865024UL   // 96 f32 (pad 512)
#define OFF_W3T      32865536UL   // 4096 f32  (end 32,881,920 < prior 33,267,712)
#define NBLK_NODES   391          // ceil(100000/256)

// ---------- binning pass 1: per-(block,bucket) histogram ----------
__global__ void __launch_bounds__(256) k_count(const int* __restrict__ ei,
                                               int* __restrict__ counts) {
    __shared__ int c[NB];
    int t = threadIdx.x;
    if (t < NB) c[t] = 0;
    __syncthreads();
    int s = blockIdx.x * EPB;
    for (int e = s + t; e < s + EPB; e += 256)
        atomicAdd(&c[ei[NE + e] >> 9], 1);
    __syncthreads();
    if (t < NB) counts[t * SB + blockIdx.x] = c[t];   // bucket-major
}

// exclusive scan of each bucket's 256 block-counts; emit bucket totals
__global__ void __launch_bounds__(256) k_scanX(const int* __restrict__ counts,
                                               int* __restrict__ pofs,
                                               int* __restrict__ btot) {
    __shared__ int s[256];
    int t = threadIdx.x, b = blockIdx.x;
    int v = counts[b * SB + t];
    s[t] = v;
    __syncthreads();
    for (int off = 1; off < 256; off <<= 1) {
        int x = (t >= off) ? s[t - off] : 0;
        __syncthreads();
        s[t] += x;
        __syncthreads();
    }
    pofs[b * SB + t] = s[t] - v;
    if (t == 255) btot[b] = s[255];
}

// exclusive scan over 196 bucket totals -> bucket bases; row_off[NN]=NE
__global__ void __launch_bounds__(256) k_scanY(const int* __restrict__ btot,
                                               int* __restrict__ bbase,
                                               int* __restrict__ row_off) {
    __shared__ int s[256];
    int t = threadIdx.x;
    int v = (t < NB) ? btot[t] : 0;
    s[t] = v;
    __syncthreads();
    for (int off = 1; off < 256; off <<= 1) {
        int x = (t >= off) ? s[t - off] : 0;
        __syncthreads();
        s[t] += x;
        __syncthreads();
    }
    if (t < NB) bbase[t] = s[t] - v;
    if (t == NB - 1) bbase[NB] = s[t];
    if (t == 0) row_off[NN] = NE;
}

// binning pass 2: scatter edges into bucket-grouped packed array.
// each (block,bucket) writes a private contiguous run -> ~no write amplification
__global__ void __launch_bounds__(256) k_scatter(const int* __restrict__ ei,
                                                 const int* __restrict__ pofs,
                                                 const int* __restrict__ bbase,
                                                 int* __restrict__ pk) {
    __shared__ int cur[NB];
    int t = threadIdx.x, blk = blockIdx.x;
    if (t < NB) cur[t] = bbase[t] + pofs[t * SB + blk];
    __syncthreads();
    int s = blk * EPB;
    for (int e = s + t; e < s + EPB; e += 256) {
        int src = ei[e], dst = ei[NE + e];
        int b = dst >> 9;
        int pos = atomicAdd(&cur[b], 1);
        pk[pos] = (src << 9) | (dst & 511);   // src<17 bits, local<9 bits
    }
}

// per-bucket node-level counting sort: row_off + csr (csr aliases pk in-place)
__global__ void __launch_bounds__(256) k_bucket(int* pk,               // in: packed, out: csr
                                                const int* __restrict__ bbase,
                                                int* __restrict__ row_off) {
    __shared__ int cnt[512];
    __shared__ int ts[256];
    __shared__ int stage[BCAP];
    int t = threadIdx.x, b = blockIdx.x;
    int base = bbase[b], end = bbase[b + 1];
    cnt[t] = 0; cnt[t + 256] = 0;
    __syncthreads();
    for (int e = base + t; e < end; e += 256)
        atomicAdd(&cnt[pk[e] & 511], 1);
    __syncthreads();
    int a0 = cnt[2 * t], a1 = cnt[2 * t + 1];
    int p = a0 + a1;
    ts[t] = p;
    __syncthreads();
    for (int off = 1; off < 256; off <<= 1) {
        int x = (t >= off) ? ts[t - off] : 0;
        __syncthreads();
        ts[t] += x;
        __syncthreads();
    }
    int ex = ts[t] - p;                 // edges in this bucket before node pair
    cnt[2 * t] = ex;                    // reuse cnt[] as within-bucket cursors
    cnt[2 * t + 1] = ex + a0;
    int n0 = b * 512 + 2 * t;
    if (n0 < NN)     row_off[n0]     = base + ex;
    if (n0 + 1 < NN) row_off[n0 + 1] = base + ex + a0;
    __syncthreads();
    for (int e = base + t; e < end; e += 256) {
        int v = pk[e];
        int pos = atomicAdd(&cnt[v & 511], 1);
        stage[pos] = v >> 9;
    }
    __syncthreads();
    int sz = end - base;
    for (int i = t; i < sz; i += 256) pk[base + i] = stage[i];  // coalesced csr write
}

// ---------- weight prep: transposes + fused chain matrices ----------
__global__ void k_prep(const float* __restrict__ W1, const float* __restrict__ W2,
                       const float* __restrict__ W3, const float* __restrict__ b3,
                       float* __restrict__ W1T, float* __restrict__ W2T,
                       float* __restrict__ MT, float* __restrict__ C,
                       float* __restrict__ W3T) {
    int t = threadIdx.x;          // 1024 threads
    int i = t >> 5, j = t & 31;
    for (int l = 0; l < 3; l++) {
        const float* w1r = W1 + (l + 1) * HH * DD + i * DD;
        const float* w3c = W3 + l * DD * HH + j;
        float m = 0.f;
        for (int k = 0; k < DD; k++) m += w1r[k] * w3c[k * HH];
        MT[l * 1024 + j * 32 + i] = m;
    }
    if (t < 96) {
        int l = t >> 5, ii = t & 31;
        const float* w1r = W1 + (l + 1) * HH * DD + ii * DD;
        const float* bb = b3 + l * DD;
        float c = 0.f;
        for (int k = 0; k < DD; k++) c += w1r[k] * bb[k];
        C[l * 32 + ii] = c;
    }
    for (int idx = t; idx < 4096; idx += 1024) {
        int jj = idx >> 7, kk = idx & 127;
        W1T[kk * 32 + jj] = W1[jj * 128 + kk];
    }
    for (int l = 0; l < 4; l++)
        W2T[l * 1024 + j * 32 + i] = W2[l * 1024 + t];
    for (int idx = t; idx < 4096; idx += 1024) {
        int jj = idx >> 5, kk = idx & 31;
        W3T[kk * 128 + jj] = W3[3 * 4096 + jj * 32 + kk];
    }
}

// ---------- P = X @ W1[0]^T ----------
__global__ void __launch_bounds__(256) k_P(const float* __restrict__ X,
                                           const float* __restrict__ W1T,
                                           float* __restrict__ P) {
    int n = blockIdx.x * 256 + threadIdx.x;
    if (n >= NN) return;
    const float4* Xr = (const float4*)(X + (size_t)n * DD);
    const float4* W = (const float4*)W1T;
    float4 acc[8];
#pragma unroll
    for (int j = 0; j < 8; j++) acc[j] = make_float4(0.f, 0.f, 0.f, 0.f);
#pragma unroll 4
    for (int k4 = 0; k4 < 32; k4++) {
        float4 x = Xr[k4];
#pragma unroll
        for (int j = 0; j < 8; j++) {
            float4 w0 = W[(4 * k4 + 0) * 8 + j];
            float4 w1 = W[(4 * k4 + 1) * 8 + j];
            float4 w2 = W[(4 * k4 + 2) * 8 + j];
            float4 w3 = W[(4 * k4 + 3) * 8 + j];
            acc[j].x += x.x * w0.x + x.y * w1.x + x.z * w2.x + x.w * w3.x;
            acc[j].y += x.x * w0.y + x.y * w1.y + x.z * w2.y + x.w * w3.y;
            acc[j].z += x.x * w0.z + x.y * w1.z + x.z * w2.z + x.w * w3.z;
            acc[j].w += x.x * w0.w + x.y * w1.w + x.z * w2.w + x.w * w3.w;
        }
    }
    float4* Pr = (float4*)(P + (size_t)n * HH);
#pragma unroll
    for (int j = 0; j < 8; j++) Pr[j] = acc[j];
}

// ---------- aggregate + t1; BN1 stats (8-way replicated) ----------
__global__ void __launch_bounds__(256) k_A(const float4* __restrict__ P4,
                                           const int* __restrict__ csr,
                                           const int* __restrict__ row_off,
                                           const float* __restrict__ eps,
                                           const float* __restrict__ b1, int l,
                                           float4* __restrict__ T4,
                                           float* __restrict__ gs) {
    __shared__ float ls[64];
    int t = threadIdx.x;
    if (t < 64) ls[t] = 0.f;
    __syncthreads();
    int g = t >> 3, i = t & 7;
    int n = blockIdx.x * 32 + g;
    float e1 = 1.f + eps[l];
    int e0 = row_off[n], eend = row_off[n + 1];
    float4 p = P4[(size_t)n * 8 + i];
    float4 acc;
    acc.x = e1 * p.x; acc.y = e1 * p.y; acc.z = e1 * p.z; acc.w = e1 * p.w;
    int e = e0;
    for (; e + 4 <= eend; e += 4) {          // 4 outstanding gathers
        int s0 = csr[e], s1 = csr[e + 1], s2 = csr[e + 2], s3 = csr[e + 3];
        float4 q0 = P4[(size_t)s0 * 8 + i];
        float4 q1 = P4[(size_t)s1 * 8 + i];
        float4 q2 = P4[(size_t)s2 * 8 + i];
        float4 q3 = P4[(size_t)s3 * 8 + i];
        acc.x += (q0.x + q1.x) + (q2.x + q3.x);
        acc.y += (q0.y + q1.y) + (q2.y + q3.y);
        acc.z += (q0.z + q1.z) + (q2.z + q3.z);
        acc.w += (q0.w + q1.w) + (q2.w + q3.w);
    }
    for (; e < eend; e++) {
        int s = csr[e];
        float4 q = P4[(size_t)s * 8 + i];
        acc.x += q.x; acc.y += q.y; acc.z += q.z; acc.w += q.w;
    }
    float4 bb = ((const float4*)(b1 + l * 32))[i];
    acc.x += bb.x; acc.y += bb.y; acc.z += bb.z; acc.w += bb.w;
    T4[(size_t)n * 8 + i] = acc;
    // stats: butterfly over node-group bits (8,16,32), then 8 lanes/wave commit
    float sx = acc.x, sy = acc.y, sz = acc.z, sw = acc.w;
    float qx = acc.x * acc.x, qy = acc.y * acc.y, qz = acc.z * acc.z, qw = acc.w * acc.w;
#pragma unroll
    for (int off = 8; off < 64; off <<= 1) {
        sx += __shfl_xor(sx, off); sy += __shfl_xor(sy, off);
        sz += __shfl_xor(sz, off); sw += __shfl_xor(sw, off);
        qx += __shfl_xor(qx, off); qy += __shfl_xor(qy, off);
        qz += __shfl_xor(qz, off); qw += __shfl_xor(qw, off);
    }
    if ((t & 56) == 0) {                     // lanes 0..7 of each wave
        atomicAdd(&ls[4 * i + 0], sx); atomicAdd(&ls[4 * i + 1], sy);
        atomicAdd(&ls[4 * i + 2], sz); atomicAdd(&ls[4 * i + 3], sw);
        atomicAdd(&ls[32 + 4 * i + 0], qx); atomicAdd(&ls[32 + 4 * i + 1], qy);
        atomicAdd(&ls[32 + 4 * i + 2], qz); atomicAdd(&ls[32 + 4 * i + 3], qw);
    }
    __syncthreads();
    if (t < 64) atomicAdd(&gs[(blockIdx.x & 7) * 64 + t], ls[t]);
}

// ---------- t2 = relu(bn1(t1)) @ W2^T + b2 (in-place); BN2 stats ----------
__global__ void __launch_bounds__(256) k_D(float* __restrict__ T,
                                           const float* __restrict__ W2T,
                                           const float* __restrict__ b2,
                                           const float* __restrict__ g1,
                                           const float* __restrict__ bt1, int l,
                                           float* __restrict__ gs) {
    __shared__ float sc[32], sh[32], ls[64];
    int t = threadIdx.x;
    if (t < 32) {
        float s0 = 0.f, s1 = 0.f;
#pragma unroll
        for (int r = 0; r < 8; r++) { s0 += gs[r * 64 + t]; s1 += gs[r * 64 + 32 + t]; }
        float m = s0 * (1.f / NN);
        float var = s1 * (1.f / NN) - m * m;
        float s = g1[l * 32 + t] * rsqrtf(var + 1e-5f);
        sc[t] = s; sh[t] = bt1[l * 32 + t] - m * s;
    } else if (t < 96) {
        ls[t - 32] = 0.f;
    }
    __syncthreads();
    int n = blockIdx.x * 256 + t;
    float4 acc[8];
    if (n < NN) {
        float4* Tr = (float4*)(T + (size_t)n * 32);
        float a1[32];
#pragma unroll
        for (int k4 = 0; k4 < 8; k4++) {
            float4 x = Tr[k4];
            a1[4 * k4 + 0] = fmaxf(x.x * sc[4 * k4 + 0] + sh[4 * k4 + 0], 0.f);
            a1[4 * k4 + 1] = fmaxf(x.y * sc[4 * k4 + 1] + sh[4 * k4 + 1], 0.f);
            a1[4 * k4 + 2] = fmaxf(x.z * sc[4 * k4 + 2] + sh[4 * k4 + 2], 0.f);
            a1[4 * k4 + 3] = fmaxf(x.w * sc[4 * k4 + 3] + sh[4 * k4 + 3], 0.f);
        }
        const float4* Wt = (const float4*)(W2T + l * 1024);
        const float4* b24 = (const float4*)(b2 + l * 32);
#pragma unroll
        for (int j = 0; j < 8; j++) acc[j] = b24[j];
#pragma unroll
        for (int k = 0; k < 32; k++) {
            float a = a1[k];
#pragma unroll
            for (int j = 0; j < 8; j++) {
                float4 w = Wt[k * 8 + j];
                acc[j].x += a * w.x; acc[j].y += a * w.y;
                acc[j].z += a * w.z; acc[j].w += a * w.w;
            }
        }
#pragma unroll
        for (int j = 0; j < 8; j++) Tr[j] = acc[j];
    } else {
#pragma unroll
        for (int j = 0; j < 8; j++) acc[j] = make_float4(0.f, 0.f, 0.f, 0.f);
    }
#pragma unroll
    for (int j = 0; j < 8; j++) {
        float vx = acc[j].x, vy = acc[j].y, vz = acc[j].z, vw = acc[j].w;
        float qx = vx * vx, qy = vy * vy, qz = vz * vz, qw = vw * vw;
#pragma unroll
        for (int off = 1; off < 64; off <<= 1) {
            vx += __shfl_xor(vx, off); vy += __shfl_xor(vy, off);
            vz += __shfl_xor(vz, off); vw += __shfl_xor(vw, off);
            qx += __shfl_xor(qx, off); qy += __shfl_xor(qy, off);
            qz += __shfl_xor(qz, off); qw += __shfl_xor(qw, off);
        }
        if ((t & 63) == 0) {
            atomicAdd(&ls[4 * j + 0], vx); atomicAdd(&ls[4 * j + 1], vy);
            atomicAdd(&ls[4 * j + 2], vz); atomicAdd(&ls[4 * j + 3], vw);
            atomicAdd(&ls[32 + 4 * j + 0], qx); atomicAdd(&ls[32 + 4 * j + 1], qy);
            atomicAdd(&ls[32 + 4 * j + 2], qz); atomicAdd(&ls[32 + 4 * j + 3], qw);
        }
    }
    __syncthreads();
    if (t < 64) atomicAdd(&gs[512 + t], ls[t]);
}

// ---------- a2 = relu(bn2(t2)); l<3: P = M a2 + c ; l==3: out = W3 a2 + b3 ----------
__global__ void __launch_bounds__(256) k_F(const float* __restrict__ T,
                                           const float* __restrict__ g2,
                                           const float* __restrict__ bt2, int l,
                                           const float* __restrict__ gs,
                                           const float* __restrict__ MT,
                                           const float* __restrict__ C,
                                           const float* __restrict__ W3T,
                                           const float* __restrict__ b3,
                                           float* __restrict__ P,
                                           float* __restrict__ out) {
    __shared__ float sc[32], sh[32];
    int t = threadIdx.x;
    if (t < 32) {
        float m = gs[512 + t] * (1.f / NN);
        float var = gs[544 + t] * (1.f / NN) - m * m;
        float s = g2[l * 32 + t] * rsqrtf(var + 1e-5f);
        sc[t] = s; sh[t] = bt2[l * 32 + t] - m * s;
    }
    __syncthreads();
    int n = blockIdx.x * 256 + t;
    if (n >= NN) return;
    float a2[32];
    const float4* Tr = (const float4*)(T + (size_t)n * 32);
#pragma unroll
    for (int k4 = 0; k4 < 8; k4++) {
        float4 x = Tr[k4];
        a2[4 * k4 + 0] = fmaxf(x.x * sc[4 * k4 + 0] + sh[4 * k4 + 0], 0.f);
        a2[4 * k4 + 1] = fmaxf(x.y * sc[4 * k4 + 1] + sh[4 * k4 + 1], 0.f);
        a2[4 * k4 + 2] = fmaxf(x.z * sc[4 * k4 + 2] + sh[4 * k4 + 2], 0.f);
        a2[4 * k4 + 3] = fmaxf(x.w * sc[4 * k4 + 3] + sh[4 * k4 + 3], 0.f);
    }
    if (l < 3) {
        const float4* Mt = (const float4*)(MT + l * 1024);
        const float4* C4 = (const float4*)(C + l * 32);
        float4 acc[8];
#pragma unroll
        for (int j = 0; j < 8; j++) acc[j] = C4[j];
#pragma unroll
        for (int k = 0; k < 32; k++) {
            float a = a2[k];
#pragma unroll
            for (int j = 0; j < 8; j++) {
                float4 w = Mt[k * 8 + j];
                acc[j].x += a * w.x; acc[j].y += a * w.y;
                acc[j].z += a * w.z; acc[j].w += a * w.w;
            }
        }
        float4* Pr = (float4*)(P + (size_t)n * 32);
#pragma unroll
        for (int j = 0; j < 8; j++) Pr[j] = acc[j];
    } else {
        const float4* Wt = (const float4*)W3T;
        const float4* b34 = (const float4*)(b3 + 3 * 128);
        float4* Or = (float4*)(out + (size_t)n * 128);
#pragma unroll 4
        for (int j4 = 0; j4 < 32; j4++) {
            float4 acc = b34[j4];
#pragma unroll
            for (int k = 0; k < 32; k++) {
                float4 w = Wt[k * 32 + j4];
                float a = a2[k];
                acc.x += a * w.x; acc.y += a * w.y;
                acc.z += a * w.z; acc.w += a * w.w;
            }
            Or[j4] = acc;
        }
    }
}

extern "C" void kernel_launch(void* const* d_in, const int* in_sizes, int n_in,
                              void* d_out, int out_size, void* d_ws, size_t ws_size,
                              hipStream_t stream) {
    const float* X   = (const float*)d_in[0];
    const int*   EI  = (const int*)d_in[1];
    const float* eps = (const float*)d_in[2];
    const float* W1  = (const float*)d_in[3];
    const float* b1  = (const float*)d_in[4];
    const float* g1  = (const float*)d_in[5];
    const float* bt1 = (const float*)d_in[6];
    const float* W2  = (const float*)d_in[7];
    const float* b2  = (const float*)d_in[8];
    const float* g2  = (const float*)d_in[9];
    const float* bt2 = (const float*)d_in[10];
    const float* W3  = (const float*)d_in[11];
    const float* b3  = (const float*)d_in[12];

    char* ws = (char*)d_ws;
    float* P       = (float*)(ws + OFF_P);
    float* T       = (float*)(ws + OFF_T);
    int*   pk      = (int*)(ws + OFF_PK);       // packed edges, then csr (aliased)
    int*   row_off = (int*)(ws + OFF_ROWOFF);
    int*   counts  = (int*)(ws + OFF_COUNTS);
    int*   pofs    = (int*)(ws + OFF_POFS);
    int*   btot    = (int*)(ws + OFF_BTOT);
    int*   bbase   = (int*)(ws + OFF_BBASE);
    float* stats   = (float*)(ws + OFF_STATS);
    float* W1T     = (float*)(ws + OFF_W1T);
    float* W2T     = (float*)(ws + OFF_W2T);
    float* MT      = (float*)(ws + OFF_MT);
    float* C       = (float*)(ws + OFF_C);
    float* W3T     = (float*)(ws + OFF_W3T);

    hipMemsetAsync(ws + OFF_STATS, 0, 16384, stream);

    k_count<<<SB, 256, 0, stream>>>(EI, counts);
    k_prep<<<1, 1024, 0, stream>>>(W1, W2, W3, b3, W1T, W2T, MT, C, W3T);
    k_scanX<<<NB, 256, 0, stream>>>(counts, pofs, btot);
    k_scanY<<<1, 256, 0, stream>>>(btot, bbase, row_off);
    k_scatter<<<SB, 256, 0, stream>>>(EI, pofs, bbase, pk);
    k_bucket<<<NB, 256, 0, stream>>>(pk, bbase, row_off);
    k_P<<<NBLK_NODES, 256, 0, stream>>>(X, W1T, P);

    for (int l = 0; l < 4; l++) {
        float* gs = stats + l * 1024;
        k_A<<<NN / 32, 256, 0, stream>>>((const float4*)P, pk, row_off, eps, b1, l,
                                         (float4*)T, gs);
        k_D<<<NBLK_NODES, 256, 0, stream>>>(T, W2T, b2, g1, bt1, l, gs);
        k_F<<<NBLK_NODES, 256, 0, stream>>>(T, g2, bt2, l, gs, MT, C, W3T, b3, P,
                                            (float*)d_out);
    }
}

// Round 4
// 585.951 us; speedup vs baseline: 1.7575x; 1.0338x over previous
//
#include <hip/hip_runtime.h>

#define NN 100000
#define NE 1600000
#define DD 128
#define HH 32
#define NB 196        // dst buckets of 512 nodes
#define SB 256        // scatter blocks
#define EPB 6250      // edges per scatter block (SB*EPB == NE)
#define BCAP 12288    // bucket capacity for LDS stage (mean 8192, sd ~90)

// ---- workspace layout (bytes) ----
#define OFF_P        0UL          // N*32 f32 = 12,800,000
#define OFF_T        12800000UL   // N*32 f32
#define OFF_PK       25600000UL   // E i32 packed (src<<9|local) -> later aliased as csr
#define OFF_ROWOFF   32000000UL   // (N+1) i32 (pad to 400128)
#define OFF_COUNTS   32400128UL   // NB*SB i32 = 200704
#define OFF_POFS     32600832UL   // NB*SB i32
#define OFF_BTOT     32801536UL   // 196 i32 (pad 1024)
#define OFF_BBASE    32802560UL   // 197 i32 (pad 1024)
#define OFF_STATS    32803584UL   // 4*1024 f32 = 16384  (memset region)
#define OFF_W1T      32819968UL   // 4096 f32
#define OFF_W2T      32836352UL   // 4096 f32
#define OFF_MT       32852736UL   // 3072 f32
#define OFF_C        32865024UL   // 96 f32 (pad 512)
#define OFF_W3T      32865536UL   // 4096 f32
#define NBLK_NODES   391

// ---------- binning pass 1: per-(block,bucket) histogram ----------
__global__ void __launch_bounds__(256) k_count(const int* __restrict__ ei,
                                               int* __restrict__ counts) {
    __shared__ int c[NB];
    int t = threadIdx.x;
    if (t < NB) c[t] = 0;
    __syncthreads();
    int s = blockIdx.x * EPB;
    for (int e = s + t; e < s + EPB; e += 256)
        atomicAdd(&c[ei[NE + e] >> 9], 1);
    __syncthreads();
    if (t < NB) counts[t * SB + blockIdx.x] = c[t];
}

__global__ void __launch_bounds__(256) k_scanX(const int* __restrict__ counts,
                                               int* __restrict__ pofs,
                                               int* __restrict__ btot) {
    __shared__ int s[256];
    int t = threadIdx.x, b = blockIdx.x;
    int v = counts[b * SB + t];
    s[t] = v;
    __syncthreads();
    for (int off = 1; off < 256; off <<= 1) {
        int x = (t >= off) ? s[t - off] : 0;
        __syncthreads();
        s[t] += x;
        __syncthreads();
    }
    pofs[b * SB + t] = s[t] - v;
    if (t == 255) btot[b] = s[255];
}

__global__ void __launch_bounds__(256) k_scanY(const int* __restrict__ btot,
                                               int* __restrict__ bbase,
                                               int* __restrict__ row_off) {
    __shared__ int s[256];
    int t = threadIdx.x;
    int v = (t < NB) ? btot[t] : 0;
    s[t] = v;
    __syncthreads();
    for (int off = 1; off < 256; off <<= 1) {
        int x = (t >= off) ? s[t - off] : 0;
        __syncthreads();
        s[t] += x;
        __syncthreads();
    }
    if (t < NB) bbase[t] = s[t] - v;
    if (t == NB - 1) bbase[NB] = s[t];
    if (t == 0) row_off[NN] = NE;
}

__global__ void __launch_bounds__(256) k_scatter(const int* __restrict__ ei,
                                                 const int* __restrict__ pofs,
                                                 const int* __restrict__ bbase,
                                                 int* __restrict__ pk) {
    __shared__ int cur[NB];
    int t = threadIdx.x, blk = blockIdx.x;
    if (t < NB) cur[t] = bbase[t] + pofs[t * SB + blk];
    __syncthreads();
    int s = blk * EPB;
    for (int e = s + t; e < s + EPB; e += 256) {
        int src = ei[e], dst = ei[NE + e];
        int b = dst >> 9;
        int pos = atomicAdd(&cur[b], 1);
        pk[pos] = (src << 9) | (dst & 511);
    }
}

__global__ void __launch_bounds__(256) k_bucket(int* pk,
                                                const int* __restrict__ bbase,
                                                int* __restrict__ row_off) {
    __shared__ int cnt[512];
    __shared__ int ts[256];
    __shared__ int stage[BCAP];
    int t = threadIdx.x, b = blockIdx.x;
    int base = bbase[b], end = bbase[b + 1];
    cnt[t] = 0; cnt[t + 256] = 0;
    __syncthreads();
    for (int e = base + t; e < end; e += 256)
        atomicAdd(&cnt[pk[e] & 511], 1);
    __syncthreads();
    int a0 = cnt[2 * t], a1 = cnt[2 * t + 1];
    int p = a0 + a1;
    ts[t] = p;
    __syncthreads();
    for (int off = 1; off < 256; off <<= 1) {
        int x = (t >= off) ? ts[t - off] : 0;
        __syncthreads();
        ts[t] += x;
        __syncthreads();
    }
    int ex = ts[t] - p;
    cnt[2 * t] = ex;
    cnt[2 * t + 1] = ex + a0;
    int n0 = b * 512 + 2 * t;
    if (n0 < NN)     row_off[n0]     = base + ex;
    if (n0 + 1 < NN) row_off[n0 + 1] = base + ex + a0;
    __syncthreads();
    for (int e = base + t; e < end; e += 256) {
        int v = pk[e];
        int pos = atomicAdd(&cnt[v & 511], 1);
        stage[pos] = v >> 9;
    }
    __syncthreads();
    int sz = end - base;
    for (int i = t; i < sz; i += 256) pk[base + i] = stage[i];
}

// ---------- weight prep ----------
__global__ void k_prep(const float* __restrict__ W1, const float* __restrict__ W2,
                       const float* __restrict__ W3, const float* __restrict__ b3,
                       float* __restrict__ W1T, float* __restrict__ W2T,
                       float* __restrict__ MT, float* __restrict__ C,
                       float* __restrict__ W3T) {
    int t = threadIdx.x;          // 1024 threads
    int i = t >> 5, j = t & 31;
    for (int l = 0; l < 3; l++) {
        const float* w1r = W1 + (l + 1) * HH * DD + i * DD;
        const float* w3c = W3 + l * DD * HH + j;
        float m = 0.f;
        for (int k = 0; k < DD; k++) m += w1r[k] * w3c[k * HH];
        MT[l * 1024 + j * 32 + i] = m;
    }
    if (t < 96) {
        int l = t >> 5, ii = t & 31;
        const float* w1r = W1 + (l + 1) * HH * DD + ii * DD;
        const float* bb = b3 + l * DD;
        float c = 0.f;
        for (int k = 0; k < DD; k++) c += w1r[k] * bb[k];
        C[l * 32 + ii] = c;
    }
    for (int idx = t; idx < 4096; idx += 1024) {
        int jj = idx >> 7, kk = idx & 127;
        W1T[kk * 32 + jj] = W1[jj * 128 + kk];
    }
    for (int l = 0; l < 4; l++)
        W2T[l * 1024 + j * 32 + i] = W2[l * 1024 + t];
    for (int idx = t; idx < 4096; idx += 1024) {
        int jj = idx >> 5, kk = idx & 31;
        W3T[kk * 128 + jj] = W3[3 * 4096 + jj * 32 + kk];
    }
}

// ---------- P = X @ W1[0]^T : 8 lanes/node, 32 nodes/block, grid 3125 ----------
__global__ void __launch_bounds__(256) k_P(const float4* __restrict__ X4,
                                           const float4* __restrict__ W1T4,
                                           float4* __restrict__ P4) {
    __shared__ float xs[32 * 132];           // 32 rows, pad to 132 floats
    int t = threadIdx.x, blk = blockIdx.x;
#pragma unroll
    for (int q = 0; q < 4; q++) {
        int idx = t + 256 * q;
        int nd = idx >> 5, c4 = idx & 31;
        *(float4*)(xs + nd * 132 + 4 * c4) = X4[(size_t)blk * 1024 + idx];
    }
    __syncthreads();
    int i = t & 7, nd = t >> 3;
    int n = blk * 32 + nd;
    float4 acc = make_float4(0.f, 0.f, 0.f, 0.f);
#pragma unroll 8
    for (int k4 = 0; k4 < 32; k4++) {
        float4 x = *(const float4*)(xs + nd * 132 + 4 * k4);
        float4 w0 = W1T4[(4 * k4 + 0) * 8 + i];
        float4 w1 = W1T4[(4 * k4 + 1) * 8 + i];
        float4 w2 = W1T4[(4 * k4 + 2) * 8 + i];
        float4 w3 = W1T4[(4 * k4 + 3) * 8 + i];
        acc.x += x.x * w0.x + x.y * w1.x + x.z * w2.x + x.w * w3.x;
        acc.y += x.x * w0.y + x.y * w1.y + x.z * w2.y + x.w * w3.y;
        acc.z += x.x * w0.z + x.y * w1.z + x.z * w2.z + x.w * w3.z;
        acc.w += x.x * w0.w + x.y * w1.w + x.z * w2.w + x.w * w3.w;
    }
    P4[(size_t)n * 8 + i] = acc;
}

// ---------- aggregate + t1; BN1 stats (8-way replicated) ----------
__global__ void __launch_bounds__(256) k_A(const float4* __restrict__ P4,
                                           const int* __restrict__ csr,
                                           const int* __restrict__ row_off,
                                           const float* __restrict__ eps,
                                           const float* __restrict__ b1, int l,
                                           float4* __restrict__ T4,
                                           float* __restrict__ gs) {
    __shared__ float ls[64];
    int t = threadIdx.x;
    if (t < 64) ls[t] = 0.f;
    __syncthreads();
    int g = t >> 3, i = t & 7;
    int n = blockIdx.x * 32 + g;
    float e1 = 1.f + eps[l];
    int e0 = row_off[n], eend = row_off[n + 1];
    float4 p = P4[(size_t)n * 8 + i];
    float4 acc;
    acc.x = e1 * p.x; acc.y = e1 * p.y; acc.z = e1 * p.z; acc.w = e1 * p.w;
    int e = e0;
    for (; e + 4 <= eend; e += 4) {
        int s0 = csr[e], s1 = csr[e + 1], s2 = csr[e + 2], s3 = csr[e + 3];
        float4 q0 = P4[(size_t)s0 * 8 + i];
        float4 q1 = P4[(size_t)s1 * 8 + i];
        float4 q2 = P4[(size_t)s2 * 8 + i];
        float4 q3 = P4[(size_t)s3 * 8 + i];
        acc.x += (q0.x + q1.x) + (q2.x + q3.x);
        acc.y += (q0.y + q1.y) + (q2.y + q3.y);
        acc.z += (q0.z + q1.z) + (q2.z + q3.z);
        acc.w += (q0.w + q1.w) + (q2.w + q3.w);
    }
    for (; e < eend; e++) {
        int s = csr[e];
        float4 q = P4[(size_t)s * 8 + i];
        acc.x += q.x; acc.y += q.y; acc.z += q.z; acc.w += q.w;
    }
    float4 bb = ((const float4*)(b1 + l * 32))[i];
    acc.x += bb.x; acc.y += bb.y; acc.z += bb.z; acc.w += bb.w;
    T4[(size_t)n * 8 + i] = acc;
    float sx = acc.x, sy = acc.y, sz = acc.z, sw = acc.w;
    float qx = acc.x * acc.x, qy = acc.y * acc.y, qz = acc.z * acc.z, qw = acc.w * acc.w;
#pragma unroll
    for (int off = 8; off < 64; off <<= 1) {
        sx += __shfl_xor(sx, off); sy += __shfl_xor(sy, off);
        sz += __shfl_xor(sz, off); sw += __shfl_xor(sw, off);
        qx += __shfl_xor(qx, off); qy += __shfl_xor(qy, off);
        qz += __shfl_xor(qz, off); qw += __shfl_xor(qw, off);
    }
    if ((t & 56) == 0) {
        atomicAdd(&ls[4 * i + 0], sx); atomicAdd(&ls[4 * i + 1], sy);
        atomicAdd(&ls[4 * i + 2], sz); atomicAdd(&ls[4 * i + 3], sw);
        atomicAdd(&ls[32 + 4 * i + 0], qx); atomicAdd(&ls[32 + 4 * i + 1], qy);
        atomicAdd(&ls[32 + 4 * i + 2], qz); atomicAdd(&ls[32 + 4 * i + 3], qw);
    }
    __syncthreads();
    if (t < 64) atomicAdd(&gs[(blockIdx.x & 7) * 64 + t], ls[t]);
}

// ---------- t2 = relu(bn1(t1)) @ W2^T + b2; BN2 stats. 8 lanes/node, grid 3125 ----------
// NOTE: W2T4 must be passed with the layer offset applied (W2T + l*1024 floats).
__global__ void __launch_bounds__(256) k_D(float4* __restrict__ T4,
                                           const float4* __restrict__ W2T4,
                                           const float* __restrict__ b2,
                                           const float* __restrict__ g1,
                                           const float* __restrict__ bt1, int l,
                                           float* __restrict__ gs) {
    __shared__ float sc[32], sh[32], ls[64], a1s[32 * 33];
    int t = threadIdx.x;
    if (t < 32) {
        float s0 = 0.f, s1 = 0.f;
#pragma unroll
        for (int r = 0; r < 8; r++) { s0 += gs[r * 64 + t]; s1 += gs[r * 64 + 32 + t]; }
        float m = s0 * (1.f / NN);
        float var = s1 * (1.f / NN) - m * m;
        float s = g1[l * 32 + t] * rsqrtf(var + 1e-5f);
        sc[t] = s; sh[t] = bt1[l * 32 + t] - m * s;
    } else if (t >= 64 && t < 128) {
        ls[t - 64] = 0.f;
    }
    __syncthreads();
    int i = t & 7, g = t >> 3;
    int n = blockIdx.x * 32 + g;
    float4 x = T4[(size_t)n * 8 + i];
    a1s[g * 33 + 4 * i + 0] = fmaxf(x.x * sc[4 * i + 0] + sh[4 * i + 0], 0.f);
    a1s[g * 33 + 4 * i + 1] = fmaxf(x.y * sc[4 * i + 1] + sh[4 * i + 1], 0.f);
    a1s[g * 33 + 4 * i + 2] = fmaxf(x.z * sc[4 * i + 2] + sh[4 * i + 2], 0.f);
    a1s[g * 33 + 4 * i + 3] = fmaxf(x.w * sc[4 * i + 3] + sh[4 * i + 3], 0.f);
    __syncthreads();
    const float4* b24 = (const float4*)(b2 + l * 32);
    float4 acc = b24[i];
#pragma unroll 8
    for (int k = 0; k < 32; k++) {
        float a = a1s[g * 33 + k];
        float4 w = W2T4[k * 8 + i];
        acc.x += a * w.x; acc.y += a * w.y; acc.z += a * w.z; acc.w += a * w.w;
    }
    T4[(size_t)n * 8 + i] = acc;
    float sx = acc.x, sy = acc.y, sz = acc.z, sw = acc.w;
    float qx = acc.x * acc.x, qy = acc.y * acc.y, qz = acc.z * acc.z, qw = acc.w * acc.w;
#pragma unroll
    for (int off = 8; off < 64; off <<= 1) {
        sx += __shfl_xor(sx, off); sy += __shfl_xor(sy, off);
        sz += __shfl_xor(sz, off); sw += __shfl_xor(sw, off);
        qx += __shfl_xor(qx, off); qy += __shfl_xor(qy, off);
        qz += __shfl_xor(qz, off); qw += __shfl_xor(qw, off);
    }
    if ((t & 56) == 0) {
        atomicAdd(&ls[4 * i + 0], sx); atomicAdd(&ls[4 * i + 1], sy);
        atomicAdd(&ls[4 * i + 2], sz); atomicAdd(&ls[4 * i + 3], sw);
        atomicAdd(&ls[32 + 4 * i + 0], qx); atomicAdd(&ls[32 + 4 * i + 1], qy);
        atomicAdd(&ls[32 + 4 * i + 2], qz); atomicAdd(&ls[32 + 4 * i + 3], qw);
    }
    __syncthreads();
    if (t < 64) atomicAdd(&gs[512 + (blockIdx.x & 7) * 64 + t], ls[t]);
}

// ---------- l<3: P = M·relu(bn2(t2)) + c. 8 lanes/node, grid 3125 ----------
__global__ void __launch_bounds__(256) k_Fm(const float4* __restrict__ T4,
                                            const float* __restrict__ g2,
                                            const float* __restrict__ bt2, int l,
                                            const float* __restrict__ gs,
                                            const float4* __restrict__ MT4,
                                            const float* __restrict__ C,
                                            float4* __restrict__ P4) {
    __shared__ float sc[32], sh[32], a2s[32 * 33];
    int t = threadIdx.x;
    if (t < 32) {
        float s0 = 0.f, s1 = 0.f;
#pragma unroll
        for (int r = 0; r < 8; r++) { s0 += gs[512 + r * 64 + t]; s1 += gs[512 + r * 64 + 32 + t]; }
        float m = s0 * (1.f / NN);
        float var = s1 * (1.f / NN) - m * m;
        float s = g2[l * 32 + t] * rsqrtf(var + 1e-5f);
        sc[t] = s; sh[t] = bt2[l * 32 + t] - m * s;
    }
    __syncthreads();
    int i = t & 7, g = t >> 3;
    int n = blockIdx.x * 32 + g;
    float4 x = T4[(size_t)n * 8 + i];
    a2s[g * 33 + 4 * i + 0] = fmaxf(x.x * sc[4 * i + 0] + sh[4 * i + 0], 0.f);
    a2s[g * 33 + 4 * i + 1] = fmaxf(x.y * sc[4 * i + 1] + sh[4 * i + 1], 0.f);
    a2s[g * 33 + 4 * i + 2] = fmaxf(x.z * sc[4 * i + 2] + sh[4 * i + 2], 0.f);
    a2s[g * 33 + 4 * i + 3] = fmaxf(x.w * sc[4 * i + 3] + sh[4 * i + 3], 0.f);
    __syncthreads();
    const float4* C4 = (const float4*)(C + l * 32);
    float4 acc = C4[i];
#pragma unroll 8
    for (int k = 0; k < 32; k++) {
        float a = a2s[g * 33 + k];
        float4 w = MT4[l * 256 + k * 8 + i];
        acc.x += a * w.x; acc.y += a * w.y; acc.z += a * w.z; acc.w += a * w.w;
    }
    P4[(size_t)n * 8 + i] = acc;
}

// ---------- l==3: out = W3·relu(bn2(t2)) + b3. 32 lanes/node, grid 12500 ----------
__global__ void __launch_bounds__(256) k_F3(const float* __restrict__ T,
                                            const float* __restrict__ g2,
                                            const float* __restrict__ bt2,
                                            const float* __restrict__ gs,
                                            const float4* __restrict__ W3T4,
                                            const float* __restrict__ b3,
                                            float4* __restrict__ out4) {
    __shared__ float sc[32], sh[32], a2s[8 * 33];
    int t = threadIdx.x, blk = blockIdx.x;
    if (t < 32) {
        float s0 = 0.f, s1 = 0.f;
#pragma unroll
        for (int r = 0; r < 8; r++) { s0 += gs[512 + r * 64 + t]; s1 += gs[512 + r * 64 + 32 + t]; }
        float m = s0 * (1.f / NN);
        float var = s1 * (1.f / NN) - m * m;
        float s = g2[3 * 32 + t] * rsqrtf(var + 1e-5f);
        sc[t] = s; sh[t] = bt2[3 * 32 + t] - m * s;
    }
    __syncthreads();
    int j = t & 31, g = t >> 5;
    float v = T[(size_t)blk * 256 + t];
    a2s[g * 33 + j] = fmaxf(v * sc[j] + sh[j], 0.f);
    __syncthreads();
    const float4* b34 = (const float4*)(b3 + 3 * 128);
    float4 acc = b34[j];
#pragma unroll 8
    for (int k = 0; k < 32; k++) {
        float a = a2s[g * 33 + k];
        float4 w = W3T4[k * 32 + j];
        acc.x += a * w.x; acc.y += a * w.y; acc.z += a * w.z; acc.w += a * w.w;
    }
    out4[(size_t)blk * 256 + t] = acc;
}

extern "C" void kernel_launch(void* const* d_in, const int* in_sizes, int n_in,
                              void* d_out, int out_size, void* d_ws, size_t ws_size,
                              hipStream_t stream) {
    const float* X   = (const float*)d_in[0];
    const int*   EI  = (const int*)d_in[1];
    const float* eps = (const float*)d_in[2];
    const float* W1  = (const float*)d_in[3];
    const float* b1  = (const float*)d_in[4];
    const float* g1  = (const float*)d_in[5];
    const float* bt1 = (const float*)d_in[6];
    const float* W2  = (const float*)d_in[7];
    const float* b2  = (const float*)d_in[8];
    const float* g2  = (const float*)d_in[9];
    const float* bt2 = (const float*)d_in[10];
    const float* W3  = (const float*)d_in[11];
    const float* b3  = (const float*)d_in[12];

    char* ws = (char*)d_ws;
    float* P       = (float*)(ws + OFF_P);
    float* T       = (float*)(ws + OFF_T);
    int*   pk      = (int*)(ws + OFF_PK);
    int*   row_off = (int*)(ws + OFF_ROWOFF);
    int*   counts  = (int*)(ws + OFF_COUNTS);
    int*   pofs    = (int*)(ws + OFF_POFS);
    int*   btot    = (int*)(ws + OFF_BTOT);
    int*   bbase   = (int*)(ws + OFF_BBASE);
    float* stats   = (float*)(ws + OFF_STATS);
    float* W1T     = (float*)(ws + OFF_W1T);
    float* W2T     = (float*)(ws + OFF_W2T);
    float* MT      = (float*)(ws + OFF_MT);
    float* C       = (float*)(ws + OFF_C);
    float* W3T     = (float*)(ws + OFF_W3T);

    hipMemsetAsync(ws + OFF_STATS, 0, 16384, stream);

    k_count<<<SB, 256, 0, stream>>>(EI, counts);
    k_prep<<<1, 1024, 0, stream>>>(W1, W2, W3, b3, W1T, W2T, MT, C, W3T);
    k_scanX<<<NB, 256, 0, stream>>>(counts, pofs, btot);
    k_scanY<<<1, 256, 0, stream>>>(btot, bbase, row_off);
    k_scatter<<<SB, 256, 0, stream>>>(EI, pofs, bbase, pk);
    k_bucket<<<NB, 256, 0, stream>>>(pk, bbase, row_off);
    k_P<<<3125, 256, 0, stream>>>((const float4*)X, (const float4*)W1T, (float4*)P);

    for (int l = 0; l < 4; l++) {
        float* gs = stats + l * 1024;
        k_A<<<NN / 32, 256, 0, stream>>>((const float4*)P, pk, row_off, eps, b1, l,
                                         (float4*)T, gs);
        k_D<<<3125, 256, 0, stream>>>((float4*)T,
                                      (const float4*)(W2T + (size_t)l * 1024),  // FIX: layer offset
                                      b2, g1, bt1, l, gs);
        if (l < 3)
            k_Fm<<<3125, 256, 0, stream>>>((const float4*)T, g2, bt2, l, gs,
                                           (const float4*)MT, C, (float4*)P);
        else
            k_F3<<<12500, 256, 0, stream>>>(T, g2, bt2, gs, (const float4*)W3T, b3,
                                            (float4*)d_out);
    }
}

// Round 5
// 564.156 us; speedup vs baseline: 1.8254x; 1.0386x over previous
//
#include <hip/hip_runtime.h>

#define NN 100000
#define NE 1600000
#define DD 128
#define HH 32
#define NB 196        // dst buckets of 512 nodes
#define SB 256        // scatter blocks
#define EPB 6250      // edges per scatter block (SB*EPB == NE)
#define BCAP 12288    // bucket capacity for LDS stage (mean 8192, sd ~90)

// ---- workspace layout (bytes) ----
#define OFF_P        0UL          // N*32 f32 = 12,800,000
#define OFF_T        12800000UL   // N*32 f32
#define OFF_PK       25600000UL   // E i32 packed (src<<9|local) -> later aliased as csr
#define OFF_ROWOFF   32000000UL   // (N+1) i32 (pad to 400128)
#define OFF_COUNTS   32400128UL   // NB*SB i32 = 200704
#define OFF_POFS     32600832UL   // NB*SB i32
#define OFF_BTOT     32801536UL   // 196 i32 (pad 1024)
#define OFF_BBASE    32802560UL   // 197 i32 (pad 1024)
#define OFF_STATS    32803584UL   // 4*1024 f32 = 16384  (memset region)
#define OFF_W1T      32819968UL   // 4096 f32
#define OFF_W2T      32836352UL   // 4096 f32
#define OFF_MT       32852736UL   // 3072 f32
#define OFF_C        32865024UL   // 96 f32 (pad 512)
#define OFF_W3T      32865536UL   // 4096 f32
#define NBLK_NODES   391

// ---------- binning pass 1: per-(block,bucket) histogram ----------
__global__ void __launch_bounds__(256) k_count(const int* __restrict__ ei,
                                               int* __restrict__ counts) {
    __shared__ int c[NB];
    int t = threadIdx.x;
    if (t < NB) c[t] = 0;
    __syncthreads();
    int s = blockIdx.x * EPB;
    for (int e = s + t; e < s + EPB; e += 256)
        atomicAdd(&c[ei[NE + e] >> 9], 1);
    __syncthreads();
    if (t < NB) counts[t * SB + blockIdx.x] = c[t];
}

__global__ void __launch_bounds__(256) k_scanX(const int* __restrict__ counts,
                                               int* __restrict__ pofs,
                                               int* __restrict__ btot) {
    __shared__ int s[256];
    int t = threadIdx.x, b = blockIdx.x;
    int v = counts[b * SB + t];
    s[t] = v;
    __syncthreads();
    for (int off = 1; off < 256; off <<= 1) {
        int x = (t >= off) ? s[t - off] : 0;
        __syncthreads();
        s[t] += x;
        __syncthreads();
    }
    pofs[b * SB + t] = s[t] - v;
    if (t == 255) btot[b] = s[255];
}

__global__ void __launch_bounds__(256) k_scanY(const int* __restrict__ btot,
                                               int* __restrict__ bbase,
                                               int* __restrict__ row_off) {
    __shared__ int s[256];
    int t = threadIdx.x;
    int v = (t < NB) ? btot[t] : 0;
    s[t] = v;
    __syncthreads();
    for (int off = 1; off < 256; off <<= 1) {
        int x = (t >= off) ? s[t - off] : 0;
        __syncthreads();
        s[t] += x;
        __syncthreads();
    }
    if (t < NB) bbase[t] = s[t] - v;
    if (t == NB - 1) bbase[NB] = s[t];
    if (t == 0) row_off[NN] = NE;
}

__global__ void __launch_bounds__(256) k_scatter(const int* __restrict__ ei,
                                                 const int* __restrict__ pofs,
                                                 const int* __restrict__ bbase,
                                                 int* __restrict__ pk) {
    __shared__ int cur[NB];
    int t = threadIdx.x, blk = blockIdx.x;
    if (t < NB) cur[t] = bbase[t] + pofs[t * SB + blk];
    __syncthreads();
    int s = blk * EPB;
    for (int e = s + t; e < s + EPB; e += 256) {
        int src = ei[e], dst = ei[NE + e];
        int b = dst >> 9;
        int pos = atomicAdd(&cur[b], 1);
        pk[pos] = (src << 9) | (dst & 511);
    }
}

__global__ void __launch_bounds__(256) k_bucket(int* pk,
                                                const int* __restrict__ bbase,
                                                int* __restrict__ row_off) {
    __shared__ int cnt[512];
    __shared__ int ts[256];
    __shared__ int stage[BCAP];
    int t = threadIdx.x, b = blockIdx.x;
    int base = bbase[b], end = bbase[b + 1];
    cnt[t] = 0; cnt[t + 256] = 0;
    __syncthreads();
    for (int e = base + t; e < end; e += 256)
        atomicAdd(&cnt[pk[e] & 511], 1);
    __syncthreads();
    int a0 = cnt[2 * t], a1 = cnt[2 * t + 1];
    int p = a0 + a1;
    ts[t] = p;
    __syncthreads();
    for (int off = 1; off < 256; off <<= 1) {
        int x = (t >= off) ? ts[t - off] : 0;
        __syncthreads();
        ts[t] += x;
        __syncthreads();
    }
    int ex = ts[t] - p;
    cnt[2 * t] = ex;
    cnt[2 * t + 1] = ex + a0;
    int n0 = b * 512 + 2 * t;
    if (n0 < NN)     row_off[n0]     = base + ex;
    if (n0 + 1 < NN) row_off[n0 + 1] = base + ex + a0;
    __syncthreads();
    for (int e = base + t; e < end; e += 256) {
        int v = pk[e];
        int pos = atomicAdd(&cnt[v & 511], 1);
        stage[pos] = v >> 9;
    }
    __syncthreads();
    int sz = end - base;
    for (int i = t; i < sz; i += 256) pk[base + i] = stage[i];
}

// ---------- weight prep ----------
__global__ void k_prep(const float* __restrict__ W1, const float* __restrict__ W2,
                       const float* __restrict__ W3, const float* __restrict__ b3,
                       float* __restrict__ W1T, float* __restrict__ W2T,
                       float* __restrict__ MT, float* __restrict__ C,
                       float* __restrict__ W3T) {
    int t = threadIdx.x;          // 1024 threads
    int i = t >> 5, j = t & 31;
    for (int l = 0; l < 3; l++) {
        const float* w1r = W1 + (l + 1) * HH * DD + i * DD;
        const float* w3c = W3 + l * DD * HH + j;
        float m = 0.f;
        for (int k = 0; k < DD; k++) m += w1r[k] * w3c[k * HH];
        MT[l * 1024 + j * 32 + i] = m;
    }
    if (t < 96) {
        int l = t >> 5, ii = t & 31;
        const float* w1r = W1 + (l + 1) * HH * DD + ii * DD;
        const float* bb = b3 + l * DD;
        float c = 0.f;
        for (int k = 0; k < DD; k++) c += w1r[k] * bb[k];
        C[l * 32 + ii] = c;
    }
    for (int idx = t; idx < 4096; idx += 1024) {
        int jj = idx >> 7, kk = idx & 127;
        W1T[kk * 32 + jj] = W1[jj * 128 + kk];
    }
    for (int l = 0; l < 4; l++)
        W2T[l * 1024 + j * 32 + i] = W2[l * 1024 + t];
    for (int idx = t; idx < 4096; idx += 1024) {
        int jj = idx >> 5, kk = idx & 31;
        W3T[kk * 128 + jj] = W3[3 * 4096 + jj * 32 + kk];
    }
}

// ---------- P = X @ W1[0]^T : register-blocked, 128 nodes/block, grid 782 ----------
// 32 groups x 8 col-quads; each group of 8 threads shares 4 nodes.
// Per k: one coalesced 128B W read per wave + LDS x broadcasts -> W L1 traffic /4.
__global__ void __launch_bounds__(256) k_P(const float4* __restrict__ X4,
                                           const float4* __restrict__ W1T4,
                                           float4* __restrict__ P4) {
    __shared__ float xs[128 * 33];           // 16.9 KB, pitch 33 = conflict-free
    int t = threadIdx.x, blk = blockIdx.x;
    int i = t & 7, g = t >> 3;               // col-quad, node-group
    int nbase = blk * 128;
    float4 acc[4];
#pragma unroll
    for (int j = 0; j < 4; j++) acc[j] = make_float4(0.f, 0.f, 0.f, 0.f);
    for (int kt = 0; kt < 4; kt++) {         // k-tiles of 32
        __syncthreads();
#pragma unroll
        for (int q = 0; q < 4; q++) {
            int idx = t + 256 * q;           // 0..1023
            int nd = idx >> 3, c4 = idx & 7;
            int node = nbase + nd;
            if (node > NN - 1) node = NN - 1;            // tail clamp (dup reads ok)
            float4 v = X4[(size_t)node * 32 + kt * 8 + c4];
            float* dst = xs + nd * 33 + 4 * c4;
            dst[0] = v.x; dst[1] = v.y; dst[2] = v.z; dst[3] = v.w;
        }
        __syncthreads();
        const float4* Wk = W1T4 + (size_t)(kt * 32) * 8 + i;
        const float* xr0 = xs + (g * 4) * 33;
#pragma unroll
        for (int k = 0; k < 32; k++) {
            float4 w = Wk[k * 8];
            float x0 = xr0[k], x1 = xr0[33 + k], x2 = xr0[66 + k], x3 = xr0[99 + k];
            acc[0].x += x0 * w.x; acc[0].y += x0 * w.y; acc[0].z += x0 * w.z; acc[0].w += x0 * w.w;
            acc[1].x += x1 * w.x; acc[1].y += x1 * w.y; acc[1].z += x1 * w.z; acc[1].w += x1 * w.w;
            acc[2].x += x2 * w.x; acc[2].y += x2 * w.y; acc[2].z += x2 * w.z; acc[2].w += x2 * w.w;
            acc[3].x += x3 * w.x; acc[3].y += x3 * w.y; acc[3].z += x3 * w.z; acc[3].w += x3 * w.w;
        }
    }
    int node = nbase + g * 4;
#pragma unroll
    for (int j = 0; j < 4; j++)
        if (node + j < NN) P4[(size_t)(node + j) * 8 + i] = acc[j];
}

// ---------- aggregate + t1; BN1 stats (8-way replicated) ----------
__global__ void __launch_bounds__(256) k_A(const float4* __restrict__ P4,
                                           const int* __restrict__ csr,
                                           const int* __restrict__ row_off,
                                           const float* __restrict__ eps,
                                           const float* __restrict__ b1, int l,
                                           float4* __restrict__ T4,
                                           float* __restrict__ gs) {
    __shared__ float ls[64];
    int t = threadIdx.x;
    if (t < 64) ls[t] = 0.f;
    __syncthreads();
    int g = t >> 3, i = t & 7;
    int n = blockIdx.x * 32 + g;
    float e1 = 1.f + eps[l];
    int e0 = row_off[n], eend = row_off[n + 1];
    float4 p = P4[(size_t)n * 8 + i];
    float4 acc;
    acc.x = e1 * p.x; acc.y = e1 * p.y; acc.z = e1 * p.z; acc.w = e1 * p.w;
    int e = e0;
    for (; e + 4 <= eend; e += 4) {
        int s0 = csr[e], s1 = csr[e + 1], s2 = csr[e + 2], s3 = csr[e + 3];
        float4 q0 = P4[(size_t)s0 * 8 + i];
        float4 q1 = P4[(size_t)s1 * 8 + i];
        float4 q2 = P4[(size_t)s2 * 8 + i];
        float4 q3 = P4[(size_t)s3 * 8 + i];
        acc.x += (q0.x + q1.x) + (q2.x + q3.x);
        acc.y += (q0.y + q1.y) + (q2.y + q3.y);
        acc.z += (q0.z + q1.z) + (q2.z + q3.z);
        acc.w += (q0.w + q1.w) + (q2.w + q3.w);
    }
    for (; e < eend; e++) {
        int s = csr[e];
        float4 q = P4[(size_t)s * 8 + i];
        acc.x += q.x; acc.y += q.y; acc.z += q.z; acc.w += q.w;
    }
    float4 bb = ((const float4*)(b1 + l * 32))[i];
    acc.x += bb.x; acc.y += bb.y; acc.z += bb.z; acc.w += bb.w;
    T4[(size_t)n * 8 + i] = acc;
    float sx = acc.x, sy = acc.y, sz = acc.z, sw = acc.w;
    float qx = acc.x * acc.x, qy = acc.y * acc.y, qz = acc.z * acc.z, qw = acc.w * acc.w;
#pragma unroll
    for (int off = 8; off < 64; off <<= 1) {
        sx += __shfl_xor(sx, off); sy += __shfl_xor(sy, off);
        sz += __shfl_xor(sz, off); sw += __shfl_xor(sw, off);
        qx += __shfl_xor(qx, off); qy += __shfl_xor(qy, off);
        qz += __shfl_xor(qz, off); qw += __shfl_xor(qw, off);
    }
    if ((t & 56) == 0) {
        atomicAdd(&ls[4 * i + 0], sx); atomicAdd(&ls[4 * i + 1], sy);
        atomicAdd(&ls[4 * i + 2], sz); atomicAdd(&ls[4 * i + 3], sw);
        atomicAdd(&ls[32 + 4 * i + 0], qx); atomicAdd(&ls[32 + 4 * i + 1], qy);
        atomicAdd(&ls[32 + 4 * i + 2], qz); atomicAdd(&ls[32 + 4 * i + 3], qw);
    }
    __syncthreads();
    if (t < 64) atomicAdd(&gs[(blockIdx.x & 7) * 64 + t], ls[t]);
}

// ---------- t2 = relu(bn1(t1)) @ W2^T + b2; BN2 stats. 8 lanes/node, grid 3125 ----------
// NOTE: W2T4 must be passed with the layer offset applied (W2T + l*1024 floats).
__global__ void __launch_bounds__(256) k_D(float4* __restrict__ T4,
                                           const float4* __restrict__ W2T4,
                                           const float* __restrict__ b2,
                                           const float* __restrict__ g1,
                                           const float* __restrict__ bt1, int l,
                                           float* __restrict__ gs) {
    __shared__ float sc[32], sh[32], ls[64], a1s[32 * 33];
    int t = threadIdx.x;
    if (t < 32) {
        float s0 = 0.f, s1 = 0.f;
#pragma unroll
        for (int r = 0; r < 8; r++) { s0 += gs[r * 64 + t]; s1 += gs[r * 64 + 32 + t]; }
        float m = s0 * (1.f / NN);
        float var = s1 * (1.f / NN) - m * m;
        float s = g1[l * 32 + t] * rsqrtf(var + 1e-5f);
        sc[t] = s; sh[t] = bt1[l * 32 + t] - m * s;
    } else if (t >= 64 && t < 128) {
        ls[t - 64] = 0.f;
    }
    __syncthreads();
    int i = t & 7, g = t >> 3;
    int n = blockIdx.x * 32 + g;
    float4 x = T4[(size_t)n * 8 + i];
    a1s[g * 33 + 4 * i + 0] = fmaxf(x.x * sc[4 * i + 0] + sh[4 * i + 0], 0.f);
    a1s[g * 33 + 4 * i + 1] = fmaxf(x.y * sc[4 * i + 1] + sh[4 * i + 1], 0.f);
    a1s[g * 33 + 4 * i + 2] = fmaxf(x.z * sc[4 * i + 2] + sh[4 * i + 2], 0.f);
    a1s[g * 33 + 4 * i + 3] = fmaxf(x.w * sc[4 * i + 3] + sh[4 * i + 3], 0.f);
    __syncthreads();
    const float4* b24 = (const float4*)(b2 + l * 32);
    float4 acc = b24[i];
#pragma unroll 8
    for (int k = 0; k < 32; k++) {
        float a = a1s[g * 33 + k];
        float4 w = W2T4[k * 8 + i];
        acc.x += a * w.x; acc.y += a * w.y; acc.z += a * w.z; acc.w += a * w.w;
    }
    T4[(size_t)n * 8 + i] = acc;
    float sx = acc.x, sy = acc.y, sz = acc.z, sw = acc.w;
    float qx = acc.x * acc.x, qy = acc.y * acc.y, qz = acc.z * acc.z, qw = acc.w * acc.w;
#pragma unroll
    for (int off = 8; off < 64; off <<= 1) {
        sx += __shfl_xor(sx, off); sy += __shfl_xor(sy, off);
        sz += __shfl_xor(sz, off); sw += __shfl_xor(sw, off);
        qx += __shfl_xor(qx, off); qy += __shfl_xor(qy, off);
        qz += __shfl_xor(qz, off); qw += __shfl_xor(qw, off);
    }
    if ((t & 56) == 0) {
        atomicAdd(&ls[4 * i + 0], sx); atomicAdd(&ls[4 * i + 1], sy);
        atomicAdd(&ls[4 * i + 2], sz); atomicAdd(&ls[4 * i + 3], sw);
        atomicAdd(&ls[32 + 4 * i + 0], qx); atomicAdd(&ls[32 + 4 * i + 1], qy);
        atomicAdd(&ls[32 + 4 * i + 2], qz); atomicAdd(&ls[32 + 4 * i + 3], qw);
    }
    __syncthreads();
    if (t < 64) atomicAdd(&gs[512 + (blockIdx.x & 7) * 64 + t], ls[t]);
}

// ---------- l<3: P = M·relu(bn2(t2)) + c. 8 lanes/node, grid 3125 ----------
__global__ void __launch_bounds__(256) k_Fm(const float4* __restrict__ T4,
                                            const float* __restrict__ g2,
                                            const float* __restrict__ bt2, int l,
                                            const float* __restrict__ gs,
                                            const float4* __restrict__ MT4,
                                            const float* __restrict__ C,
                                            float4* __restrict__ P4) {
    __shared__ float sc[32], sh[32], a2s[32 * 33];
    int t = threadIdx.x;
    if (t < 32) {
        float s0 = 0.f, s1 = 0.f;
#pragma unroll
        for (int r = 0; r < 8; r++) { s0 += gs[512 + r * 64 + t]; s1 += gs[512 + r * 64 + 32 + t]; }
        float m = s0 * (1.f / NN);
        float var = s1 * (1.f / NN) - m * m;
        float s = g2[l * 32 + t] * rsqrtf(var + 1e-5f);
        sc[t] = s; sh[t] = bt2[l * 32 + t] - m * s;
    }
    __syncthreads();
    int i = t & 7, g = t >> 3;
    int n = blockIdx.x * 32 + g;
    float4 x = T4[(size_t)n * 8 + i];
    a2s[g * 33 + 4 * i + 0] = fmaxf(x.x * sc[4 * i + 0] + sh[4 * i + 0], 0.f);
    a2s[g * 33 + 4 * i + 1] = fmaxf(x.y * sc[4 * i + 1] + sh[4 * i + 1], 0.f);
    a2s[g * 33 + 4 * i + 2] = fmaxf(x.z * sc[4 * i + 2] + sh[4 * i + 2], 0.f);
    a2s[g * 33 + 4 * i + 3] = fmaxf(x.w * sc[4 * i + 3] + sh[4 * i + 3], 0.f);
    __syncthreads();
    const float4* C4 = (const float4*)(C + l * 32);
    float4 acc = C4[i];
#pragma unroll 8
    for (int k = 0; k < 32; k++) {
        float a = a2s[g * 33 + k];
        float4 w = MT4[l * 256 + k * 8 + i];
        acc.x += a * w.x; acc.y += a * w.y; acc.z += a * w.z; acc.w += a * w.w;
    }
    P4[(size_t)n * 8 + i] = acc;
}

// ---------- l==3: out = W3·relu(bn2(t2)) + b3. 32 lanes/node, grid 12500 ----------
__global__ void __launch_bounds__(256) k_F3(const float* __restrict__ T,
                                            const float* __restrict__ g2,
                                            const float* __restrict__ bt2,
                                            const float* __restrict__ gs,
                                            const float4* __restrict__ W3T4,
                                            const float* __restrict__ b3,
                                            float4* __restrict__ out4) {
    __shared__ float sc[32], sh[32], a2s[8 * 33];
    int t = threadIdx.x, blk = blockIdx.x;
    if (t < 32) {
        float s0 = 0.f, s1 = 0.f;
#pragma unroll
        for (int r = 0; r < 8; r++) { s0 += gs[512 + r * 64 + t]; s1 += gs[512 + r * 64 + 32 + t]; }
        float m = s0 * (1.f / NN);
        float var = s1 * (1.f / NN) - m * m;
        float s = g2[3 * 32 + t] * rsqrtf(var + 1e-5f);
        sc[t] = s; sh[t] = bt2[3 * 32 + t] - m * s;
    }
    __syncthreads();
    int j = t & 31, g = t >> 5;
    float v = T[(size_t)blk * 256 + t];
    a2s[g * 33 + j] = fmaxf(v * sc[j] + sh[j], 0.f);
    __syncthreads();
    const float4* b34 = (const float4*)(b3 + 3 * 128);
    float4 acc = b34[j];
#pragma unroll 8
    for (int k = 0; k < 32; k++) {
        float a = a2s[g * 33 + k];
        float4 w = W3T4[k * 32 + j];
        acc.x += a * w.x; acc.y += a * w.y; acc.z += a * w.z; acc.w += a * w.w;
    }
    out4[(size_t)blk * 256 + t] = acc;
}

extern "C" void kernel_launch(void* const* d_in, const int* in_sizes, int n_in,
                              void* d_out, int out_size, void* d_ws, size_t ws_size,
                              hipStream_t stream) {
    const float* X   = (const float*)d_in[0];
    const int*   EI  = (const int*)d_in[1];
    const float* eps = (const float*)d_in[2];
    const float* W1  = (const float*)d_in[3];
    const float* b1  = (const float*)d_in[4];
    const float* g1  = (const float*)d_in[5];
    const float* bt1 = (const float*)d_in[6];
    const float* W2  = (const float*)d_in[7];
    const float* b2  = (const float*)d_in[8];
    const float* g2  = (const float*)d_in[9];
    const float* bt2 = (const float*)d_in[10];
    const float* W3  = (const float*)d_in[11];
    const float* b3  = (const float*)d_in[12];

    char* ws = (char*)d_ws;
    float* P       = (float*)(ws + OFF_P);
    float* T       = (float*)(ws + OFF_T);
    int*   pk      = (int*)(ws + OFF_PK);
    int*   row_off = (int*)(ws + OFF_ROWOFF);
    int*   counts  = (int*)(ws + OFF_COUNTS);
    int*   pofs    = (int*)(ws + OFF_POFS);
    int*   btot    = (int*)(ws + OFF_BTOT);
    int*   bbase   = (int*)(ws + OFF_BBASE);
    float* stats   = (float*)(ws + OFF_STATS);
    float* W1T     = (float*)(ws + OFF_W1T);
    float* W2T     = (float*)(ws + OFF_W2T);
    float* MT      = (float*)(ws + OFF_MT);
    float* C       = (float*)(ws + OFF_C);
    float* W3T     = (float*)(ws + OFF_W3T);

    hipMemsetAsync(ws + OFF_STATS, 0, 16384, stream);

    k_count<<<SB, 256, 0, stream>>>(EI, counts);
    k_prep<<<1, 1024, 0, stream>>>(W1, W2, W3, b3, W1T, W2T, MT, C, W3T);
    k_scanX<<<NB, 256, 0, stream>>>(counts, pofs, btot);
    k_scanY<<<1, 256, 0, stream>>>(btot, bbase, row_off);
    k_scatter<<<SB, 256, 0, stream>>>(EI, pofs, bbase, pk);
    k_bucket<<<NB, 256, 0, stream>>>(pk, bbase, row_off);
    k_P<<<782, 256, 0, stream>>>((const float4*)X, (const float4*)W1T, (float4*)P);

    for (int l = 0; l < 4; l++) {
        float* gs = stats + l * 1024;
        k_A<<<NN / 32, 256, 0, stream>>>((const float4*)P, pk, row_off, eps, b1, l,
                                         (float4*)T, gs);
        k_D<<<3125, 256, 0, stream>>>((float4*)T,
                                      (const float4*)(W2T + (size_t)l * 1024),
                                      b2, g1, bt1, l, gs);
        if (l < 3)
            k_Fm<<<3125, 256, 0, stream>>>((const float4*)T, g2, bt2, l, gs,
                                           (const float4*)MT, C, (float4*)P);
        else
            k_F3<<<12500, 256, 0, stream>>>(T, g2, bt2, gs, (const float4*)W3T, b3,
                                            (float4*)d_out);
    }
}

// Round 6
// 507.919 us; speedup vs baseline: 2.0275x; 1.1107x over previous
//
#include <hip/hip_runtime.h>

#define NN 100000
#define NE 1600000
#define DD 128
#define HH 32
#define NB 196        // dst buckets of 512 nodes
#define SB 256        // scatter blocks
#define EPB 6250      // edges per scatter block (SB*EPB == NE)
#define BCAP 12288    // bucket capacity for LDS stage

// ---- workspace layout (bytes) ----
#define OFF_P        0UL
#define OFF_T        12800000UL
#define OFF_PK       25600000UL
#define OFF_ROWOFF   32000000UL
#define OFF_COUNTS   32400128UL
#define OFF_POFS     32600832UL
#define OFF_BTOT     32801536UL
#define OFF_BBASE    32802560UL
#define OFF_STATS    32803584UL
#define OFF_W1T      32819968UL
#define OFF_W2T      32836352UL
#define OFF_MT       32852736UL
#define OFF_C        32865024UL
#define OFF_W3T      32865536UL

// ---------- binning pass 1 ----------
__global__ void __launch_bounds__(256) k_count(const int* __restrict__ ei,
                                               int* __restrict__ counts) {
    __shared__ int c[NB];
    int t = threadIdx.x;
    if (t < NB) c[t] = 0;
    __syncthreads();
    int s = blockIdx.x * EPB;
    for (int e = s + t; e < s + EPB; e += 256)
        atomicAdd(&c[ei[NE + e] >> 9], 1);
    __syncthreads();
    if (t < NB) counts[t * SB + blockIdx.x] = c[t];
}

__global__ void __launch_bounds__(256) k_scanX(const int* __restrict__ counts,
                                               int* __restrict__ pofs,
                                               int* __restrict__ btot) {
    __shared__ int s[256];
    int t = threadIdx.x, b = blockIdx.x;
    int v = counts[b * SB + t];
    s[t] = v;
    __syncthreads();
    for (int off = 1; off < 256; off <<= 1) {
        int x = (t >= off) ? s[t - off] : 0;
        __syncthreads();
        s[t] += x;
        __syncthreads();
    }
    pofs[b * SB + t] = s[t] - v;
    if (t == 255) btot[b] = s[255];
}

__global__ void __launch_bounds__(256) k_scanY(const int* __restrict__ btot,
                                               int* __restrict__ bbase,
                                               int* __restrict__ row_off) {
    __shared__ int s[256];
    int t = threadIdx.x;
    int v = (t < NB) ? btot[t] : 0;
    s[t] = v;
    __syncthreads();
    for (int off = 1; off < 256; off <<= 1) {
        int x = (t >= off) ? s[t - off] : 0;
        __syncthreads();
        s[t] += x;
        __syncthreads();
    }
    if (t < NB) bbase[t] = s[t] - v;
    if (t == NB - 1) bbase[NB] = s[t];
    if (t == 0) row_off[NN] = NE;
}

__global__ void __launch_bounds__(256) k_scatter(const int* __restrict__ ei,
                                                 const int* __restrict__ pofs,
                                                 const int* __restrict__ bbase,
                                                 int* __restrict__ pk) {
    __shared__ int cur[NB];
    int t = threadIdx.x, blk = blockIdx.x;
    if (t < NB) cur[t] = bbase[t] + pofs[t * SB + blk];
    __syncthreads();
    int s = blk * EPB;
    for (int e = s + t; e < s + EPB; e += 256) {
        int src = ei[e], dst = ei[NE + e];
        int b = dst >> 9;
        int pos = atomicAdd(&cur[b], 1);
        pk[pos] = (src << 9) | (dst & 511);
    }
}

__global__ void __launch_bounds__(256) k_bucket(int* pk,
                                                const int* __restrict__ bbase,
                                                int* __restrict__ row_off) {
    __shared__ int cnt[512];
    __shared__ int ts[256];
    __shared__ int stage[BCAP];
    int t = threadIdx.x, b = blockIdx.x;
    int base = bbase[b], end = bbase[b + 1];
    cnt[t] = 0; cnt[t + 256] = 0;
    __syncthreads();
    for (int e = base + t; e < end; e += 256)
        atomicAdd(&cnt[pk[e] & 511], 1);
    __syncthreads();
    int a0 = cnt[2 * t], a1 = cnt[2 * t + 1];
    int p = a0 + a1;
    ts[t] = p;
    __syncthreads();
    for (int off = 1; off < 256; off <<= 1) {
        int x = (t >= off) ? ts[t - off] : 0;
        __syncthreads();
        ts[t] += x;
        __syncthreads();
    }
    int ex = ts[t] - p;
    cnt[2 * t] = ex;
    cnt[2 * t + 1] = ex + a0;
    int n0 = b * 512 + 2 * t;
    if (n0 < NN)     row_off[n0]     = base + ex;
    if (n0 + 1 < NN) row_off[n0 + 1] = base + ex + a0;
    __syncthreads();
    for (int e = base + t; e < end; e += 256) {
        int v = pk[e];
        int pos = atomicAdd(&cnt[v & 511], 1);
        stage[pos] = v >> 9;
    }
    __syncthreads();
    int sz = end - base;
    for (int i = t; i < sz; i += 256) pk[base + i] = stage[i];
}

// ---------- weight prep ----------
__global__ void k_prep(const float* __restrict__ W1, const float* __restrict__ W2,
                       const float* __restrict__ W3, const float* __restrict__ b3,
                       float* __restrict__ W1T, float* __restrict__ W2T,
                       float* __restrict__ MT, float* __restrict__ C,
                       float* __restrict__ W3T) {
    int t = threadIdx.x;          // 1024 threads
    int i = t >> 5, j = t & 31;
    for (int l = 0; l < 3; l++) {
        const float* w1r = W1 + (l + 1) * HH * DD + i * DD;
        const float* w3c = W3 + l * DD * HH + j;
        float m = 0.f;
        for (int k = 0; k < DD; k++) m += w1r[k] * w3c[k * HH];
        MT[l * 1024 + j * 32 + i] = m;
    }
    if (t < 96) {
        int l = t >> 5, ii = t & 31;
        const float* w1r = W1 + (l + 1) * HH * DD + ii * DD;
        const float* bb = b3 + l * DD;
        float c = 0.f;
        for (int k = 0; k < DD; k++) c += w1r[k] * bb[k];
        C[l * 32 + ii] = c;
    }
    for (int idx = t; idx < 4096; idx += 1024) {
        int jj = idx >> 7, kk = idx & 127;
        W1T[kk * 32 + jj] = W1[jj * 128 + kk];
    }
    for (int l = 0; l < 4; l++)
        W2T[l * 1024 + j * 32 + i] = W2[l * 1024 + t];
    for (int idx = t; idx < 4096; idx += 1024) {
        int jj = idx >> 5, kk = idx & 31;
        W3T[kk * 128 + jj] = W3[3 * 4096 + jj * 32 + kk];
    }
}

// ---------- P = X @ W1[0]^T : register-blocked, 128 nodes/block, grid 782 ----------
__global__ void __launch_bounds__(256) k_P(const float4* __restrict__ X4,
                                           const float4* __restrict__ W1T4,
                                           float4* __restrict__ P4) {
    __shared__ float xs[128 * 33];
    int t = threadIdx.x, blk = blockIdx.x;
    int i = t & 7, g = t >> 3;
    int nbase = blk * 128;
    float4 acc[4];
#pragma unroll
    for (int j = 0; j < 4; j++) acc[j] = make_float4(0.f, 0.f, 0.f, 0.f);
    for (int kt = 0; kt < 4; kt++) {
        __syncthreads();
#pragma unroll
        for (int q = 0; q < 4; q++) {
            int idx = t + 256 * q;
            int nd = idx >> 3, c4 = idx & 7;
            int node = nbase + nd;
            if (node > NN - 1) node = NN - 1;
            float4 v = X4[(size_t)node * 32 + kt * 8 + c4];
            float* dst = xs + nd * 33 + 4 * c4;
            dst[0] = v.x; dst[1] = v.y; dst[2] = v.z; dst[3] = v.w;
        }
        __syncthreads();
        const float4* Wk = W1T4 + (size_t)(kt * 32) * 8 + i;
        const float* xr0 = xs + (g * 4) * 33;
#pragma unroll
        for (int k = 0; k < 32; k++) {
            float4 w = Wk[k * 8];
            float x0 = xr0[k], x1 = xr0[33 + k], x2 = xr0[66 + k], x3 = xr0[99 + k];
            acc[0].x += x0 * w.x; acc[0].y += x0 * w.y; acc[0].z += x0 * w.z; acc[0].w += x0 * w.w;
            acc[1].x += x1 * w.x; acc[1].y += x1 * w.y; acc[1].z += x1 * w.z; acc[1].w += x1 * w.w;
            acc[2].x += x2 * w.x; acc[2].y += x2 * w.y; acc[2].z += x2 * w.z; acc[2].w += x2 * w.w;
            acc[3].x += x3 * w.x; acc[3].y += x3 * w.y; acc[3].z += x3 * w.z; acc[3].w += x3 * w.w;
        }
    }
    int node = nbase + g * 4;
#pragma unroll
    for (int j = 0; j < 4; j++)
        if (node + j < NN) P4[(size_t)(node + j) * 8 + i] = acc[j];
}

// ---------- aggregate + t1; BN1 stats (8-way replicated) ----------
__global__ void __launch_bounds__(256) k_A(const float4* __restrict__ P4,
                                           const int* __restrict__ csr,
                                           const int* __restrict__ row_off,
                                           const float* __restrict__ eps,
                                           const float* __restrict__ b1, int l,
                                           float4* __restrict__ T4,
                                           float* __restrict__ gs) {
    __shared__ float ls[64];
    int t = threadIdx.x;
    if (t < 64) ls[t] = 0.f;
    __syncthreads();
    int g = t >> 3, i = t & 7;
    int n = blockIdx.x * 32 + g;
    float e1 = 1.f + eps[l];
    int e0 = row_off[n], eend = row_off[n + 1];
    float4 p = P4[(size_t)n * 8 + i];
    float4 acc;
    acc.x = e1 * p.x; acc.y = e1 * p.y; acc.z = e1 * p.z; acc.w = e1 * p.w;
    int e = e0;
    for (; e + 4 <= eend; e += 4) {
        int s0 = csr[e], s1 = csr[e + 1], s2 = csr[e + 2], s3 = csr[e + 3];
        float4 q0 = P4[(size_t)s0 * 8 + i];
        float4 q1 = P4[(size_t)s1 * 8 + i];
        float4 q2 = P4[(size_t)s2 * 8 + i];
        float4 q3 = P4[(size_t)s3 * 8 + i];
        acc.x += (q0.x + q1.x) + (q2.x + q3.x);
        acc.y += (q0.y + q1.y) + (q2.y + q3.y);
        acc.z += (q0.z + q1.z) + (q2.z + q3.z);
        acc.w += (q0.w + q1.w) + (q2.w + q3.w);
    }
    for (; e < eend; e++) {
        int s = csr[e];
        float4 q = P4[(size_t)s * 8 + i];
        acc.x += q.x; acc.y += q.y; acc.z += q.z; acc.w += q.w;
    }
    float4 bb = ((const float4*)(b1 + l * 32))[i];
    acc.x += bb.x; acc.y += bb.y; acc.z += bb.z; acc.w += bb.w;
    T4[(size_t)n * 8 + i] = acc;
    float sx = acc.x, sy = acc.y, sz = acc.z, sw = acc.w;
    float qx = acc.x * acc.x, qy = acc.y * acc.y, qz = acc.z * acc.z, qw = acc.w * acc.w;
#pragma unroll
    for (int off = 8; off < 64; off <<= 1) {
        sx += __shfl_xor(sx, off); sy += __shfl_xor(sy, off);
        sz += __shfl_xor(sz, off); sw += __shfl_xor(sw, off);
        qx += __shfl_xor(qx, off); qy += __shfl_xor(qy, off);
        qz += __shfl_xor(qz, off); qw += __shfl_xor(qw, off);
    }
    if ((t & 56) == 0) {
        atomicAdd(&ls[4 * i + 0], sx); atomicAdd(&ls[4 * i + 1], sy);
        atomicAdd(&ls[4 * i + 2], sz); atomicAdd(&ls[4 * i + 3], sw);
        atomicAdd(&ls[32 + 4 * i + 0], qx); atomicAdd(&ls[32 + 4 * i + 1], qy);
        atomicAdd(&ls[32 + 4 * i + 2], qz); atomicAdd(&ls[32 + 4 * i + 3], qw);
    }
    __syncthreads();
    if (t < 64) atomicAdd(&gs[(blockIdx.x & 7) * 64 + t], ls[t]);
}

// ---------- t2 = relu(bn1(t1)) @ W2^T + b2; BN2 stats. 128 nodes/block, grid 782 ----------
// W2T4 passed with layer offset applied.
__global__ void __launch_bounds__(256) k_D(float4* __restrict__ T4,
                                           const float4* __restrict__ W2T4,
                                           const float* __restrict__ b2,
                                           const float* __restrict__ g1,
                                           const float* __restrict__ bt1, int l,
                                           float* __restrict__ gs) {
    __shared__ float sc[32], sh[32], ls[64], a1s[128 * 33];
    int t = threadIdx.x, blk = blockIdx.x;
    if (t < 32) {
        float s0 = 0.f, s1 = 0.f;
#pragma unroll
        for (int r = 0; r < 8; r++) { s0 += gs[r * 64 + t]; s1 += gs[r * 64 + 32 + t]; }
        float m = s0 * (1.f / NN);
        float var = s1 * (1.f / NN) - m * m;
        float s = g1[l * 32 + t] * rsqrtf(var + 1e-5f);
        sc[t] = s; sh[t] = bt1[l * 32 + t] - m * s;
    } else if (t >= 64 && t < 128) {
        ls[t - 64] = 0.f;
    }
    __syncthreads();
    int nbase = blk * 128;
#pragma unroll
    for (int q = 0; q < 4; q++) {
        int idx = t + 256 * q;               // 0..1023
        int nd = idx >> 3, c4 = idx & 7;
        int node = nbase + nd;
        if (node > NN - 1) node = NN - 1;    // tail clamp (dup loads ok)
        float4 x = T4[(size_t)node * 8 + c4];
        float* dst = a1s + nd * 33 + 4 * c4;
        dst[0] = fmaxf(x.x * sc[4 * c4 + 0] + sh[4 * c4 + 0], 0.f);
        dst[1] = fmaxf(x.y * sc[4 * c4 + 1] + sh[4 * c4 + 1], 0.f);
        dst[2] = fmaxf(x.z * sc[4 * c4 + 2] + sh[4 * c4 + 2], 0.f);
        dst[3] = fmaxf(x.w * sc[4 * c4 + 3] + sh[4 * c4 + 3], 0.f);
    }
    __syncthreads();
    int i = t & 7, g = t >> 3;               // col-quad, node-group (4 nodes)
    const float4* b24 = (const float4*)(b2 + l * 32);
    float4 b = b24[i];
    float4 acc[4];
#pragma unroll
    for (int j = 0; j < 4; j++) acc[j] = b;
    const float* xr0 = a1s + (g * 4) * 33;
#pragma unroll
    for (int k = 0; k < 32; k++) {
        float4 w = W2T4[k * 8 + i];
        float x0 = xr0[k], x1 = xr0[33 + k], x2 = xr0[66 + k], x3 = xr0[99 + k];
        acc[0].x += x0 * w.x; acc[0].y += x0 * w.y; acc[0].z += x0 * w.z; acc[0].w += x0 * w.w;
        acc[1].x += x1 * w.x; acc[1].y += x1 * w.y; acc[1].z += x1 * w.z; acc[1].w += x1 * w.w;
        acc[2].x += x2 * w.x; acc[2].y += x2 * w.y; acc[2].z += x2 * w.z; acc[2].w += x2 * w.w;
        acc[3].x += x3 * w.x; acc[3].y += x3 * w.y; acc[3].z += x3 * w.z; acc[3].w += x3 * w.w;
    }
    int node = nbase + g * 4;
    float sx = 0.f, sy = 0.f, sz = 0.f, sw = 0.f;
    float qx = 0.f, qy = 0.f, qz = 0.f, qw = 0.f;
#pragma unroll
    for (int j = 0; j < 4; j++) {
        if (node + j < NN) {
            T4[(size_t)(node + j) * 8 + i] = acc[j];
            sx += acc[j].x; sy += acc[j].y; sz += acc[j].z; sw += acc[j].w;
            qx += acc[j].x * acc[j].x; qy += acc[j].y * acc[j].y;
            qz += acc[j].z * acc[j].z; qw += acc[j].w * acc[j].w;
        }
    }
#pragma unroll
    for (int off = 8; off < 64; off <<= 1) {
        sx += __shfl_xor(sx, off); sy += __shfl_xor(sy, off);
        sz += __shfl_xor(sz, off); sw += __shfl_xor(sw, off);
        qx += __shfl_xor(qx, off); qy += __shfl_xor(qy, off);
        qz += __shfl_xor(qz, off); qw += __shfl_xor(qw, off);
    }
    if ((t & 56) == 0) {
        atomicAdd(&ls[4 * i + 0], sx); atomicAdd(&ls[4 * i + 1], sy);
        atomicAdd(&ls[4 * i + 2], sz); atomicAdd(&ls[4 * i + 3], sw);
        atomicAdd(&ls[32 + 4 * i + 0], qx); atomicAdd(&ls[32 + 4 * i + 1], qy);
        atomicAdd(&ls[32 + 4 * i + 2], qz); atomicAdd(&ls[32 + 4 * i + 3], qw);
    }
    __syncthreads();
    if (t < 64) atomicAdd(&gs[512 + (blk & 7) * 64 + t], ls[t]);
}

// ---------- l<3: P = M·relu(bn2(t2)) + c. 128 nodes/block, grid 782 ----------
__global__ void __launch_bounds__(256) k_Fm(const float4* __restrict__ T4,
                                            const float* __restrict__ g2,
                                            const float* __restrict__ bt2, int l,
                                            const float* __restrict__ gs,
                                            const float4* __restrict__ MT4,
                                            const float* __restrict__ C,
                                            float4* __restrict__ P4) {
    __shared__ float sc[32], sh[32], a2s[128 * 33];
    int t = threadIdx.x, blk = blockIdx.x;
    if (t < 32) {
        float s0 = 0.f, s1 = 0.f;
#pragma unroll
        for (int r = 0; r < 8; r++) { s0 += gs[512 + r * 64 + t]; s1 += gs[512 + r * 64 + 32 + t]; }
        float m = s0 * (1.f / NN);
        float var = s1 * (1.f / NN) - m * m;
        float s = g2[l * 32 + t] * rsqrtf(var + 1e-5f);
        sc[t] = s; sh[t] = bt2[l * 32 + t] - m * s;
    }
    __syncthreads();
    int nbase = blk * 128;
#pragma unroll
    for (int q = 0; q < 4; q++) {
        int idx = t + 256 * q;
        int nd = idx >> 3, c4 = idx & 7;
        int node = nbase + nd;
        if (node > NN - 1) node = NN - 1;
        float4 x = T4[(size_t)node * 8 + c4];
        float* dst = a2s + nd * 33 + 4 * c4;
        dst[0] = fmaxf(x.x * sc[4 * c4 + 0] + sh[4 * c4 + 0], 0.f);
        dst[1] = fmaxf(x.y * sc[4 * c4 + 1] + sh[4 * c4 + 1], 0.f);
        dst[2] = fmaxf(x.z * sc[4 * c4 + 2] + sh[4 * c4 + 2], 0.f);
        dst[3] = fmaxf(x.w * sc[4 * c4 + 3] + sh[4 * c4 + 3], 0.f);
    }
    __syncthreads();
    int i = t & 7, g = t >> 3;
    const float4* C4 = (const float4*)(C + l * 32);
    float4 c0 = C4[i];
    float4 acc[4];
#pragma unroll
    for (int j = 0; j < 4; j++) acc[j] = c0;
    const float* xr0 = a2s + (g * 4) * 33;
    const float4* Mt = MT4 + l * 256;
#pragma unroll
    for (int k = 0; k < 32; k++) {
        float4 w = Mt[k * 8 + i];
        float x0 = xr0[k], x1 = xr0[33 + k], x2 = xr0[66 + k], x3 = xr0[99 + k];
        acc[0].x += x0 * w.x; acc[0].y += x0 * w.y; acc[0].z += x0 * w.z; acc[0].w += x0 * w.w;
        acc[1].x += x1 * w.x; acc[1].y += x1 * w.y; acc[1].z += x1 * w.z; acc[1].w += x1 * w.w;
        acc[2].x += x2 * w.x; acc[2].y += x2 * w.y; acc[2].z += x2 * w.z; acc[2].w += x2 * w.w;
        acc[3].x += x3 * w.x; acc[3].y += x3 * w.y; acc[3].z += x3 * w.z; acc[3].w += x3 * w.w;
    }
    int node = nbase + g * 4;
#pragma unroll
    for (int j = 0; j < 4; j++)
        if (node + j < NN) P4[(size_t)(node + j) * 8 + i] = acc[j];
}

// ---------- l==3: out = W3·relu(bn2(t2)) + b3. 32 nodes/block, grid 3125 ----------
__global__ void __launch_bounds__(256) k_F3(const float4* __restrict__ T4,
                                            const float* __restrict__ g2,
                                            const float* __restrict__ bt2,
                                            const float* __restrict__ gs,
                                            const float4* __restrict__ W3T4,
                                            const float* __restrict__ b3,
                                            float4* __restrict__ out4) {
    __shared__ float sc[32], sh[32], a2s[32 * 33];
    int t = threadIdx.x, blk = blockIdx.x;
    if (t < 32) {
        float s0 = 0.f, s1 = 0.f;
#pragma unroll
        for (int r = 0; r < 8; r++) { s0 += gs[512 + r * 64 + t]; s1 += gs[512 + r * 64 + 32 + t]; }
        float m = s0 * (1.f / NN);
        float var = s1 * (1.f / NN) - m * m;
        float s = g2[3 * 32 + t] * rsqrtf(var + 1e-5f);
        sc[t] = s; sh[t] = bt2[3 * 32 + t] - m * s;
    }
    __syncthreads();
    {
        int nd = t >> 3, c4 = t & 7;         // 32 nodes x 8 quads
        float4 x = T4[(size_t)(blk * 32 + nd) * 8 + c4];
        float* dst = a2s + nd * 33 + 4 * c4;
        dst[0] = fmaxf(x.x * sc[4 * c4 + 0] + sh[4 * c4 + 0], 0.f);
        dst[1] = fmaxf(x.y * sc[4 * c4 + 1] + sh[4 * c4 + 1], 0.f);
        dst[2] = fmaxf(x.z * sc[4 * c4 + 2] + sh[4 * c4 + 2], 0.f);
        dst[3] = fmaxf(x.w * sc[4 * c4 + 3] + sh[4 * c4 + 3], 0.f);
    }
    __syncthreads();
    int j = t & 31, g = t >> 5;              // out col-quad, node-group (4 nodes)
    const float4* b34 = (const float4*)(b3 + 3 * 128);
    float4 b = b34[j];
    float4 acc[4];
#pragma unroll
    for (int jj = 0; jj < 4; jj++) acc[jj] = b;
    const float* xr0 = a2s + (g * 4) * 33;
#pragma unroll
    for (int k = 0; k < 32; k++) {
        float4 w = W3T4[k * 32 + j];
        float x0 = xr0[k], x1 = xr0[33 + k], x2 = xr0[66 + k], x3 = xr0[99 + k];
        acc[0].x += x0 * w.x; acc[0].y += x0 * w.y; acc[0].z += x0 * w.z; acc[0].w += x0 * w.w;
        acc[1].x += x1 * w.x; acc[1].y += x1 * w.y; acc[1].z += x1 * w.z; acc[1].w += x1 * w.w;
        acc[2].x += x2 * w.x; acc[2].y += x2 * w.y; acc[2].z += x2 * w.z; acc[2].w += x2 * w.w;
        acc[3].x += x3 * w.x; acc[3].y += x3 * w.y; acc[3].z += x3 * w.z; acc[3].w += x3 * w.w;
    }
    size_t node = (size_t)blk * 32 + g * 4;  // grid exact: 3125*32 == NN
#pragma unroll
    for (int jj = 0; jj < 4; jj++)
        out4[(node + jj) * 32 + j] = acc[jj];
}

extern "C" void kernel_launch(void* const* d_in, const int* in_sizes, int n_in,
                              void* d_out, int out_size, void* d_ws, size_t ws_size,
                              hipStream_t stream) {
    const float* X   = (const float*)d_in[0];
    const int*   EI  = (const int*)d_in[1];
    const float* eps = (const float*)d_in[2];
    const float* W1  = (const float*)d_in[3];
    const float* b1  = (const float*)d_in[4];
    const float* g1  = (const float*)d_in[5];
    const float* bt1 = (const float*)d_in[6];
    const float* W2  = (const float*)d_in[7];
    const float* b2  = (const float*)d_in[8];
    const float* g2  = (const float*)d_in[9];
    const float* bt2 = (const float*)d_in[10];
    const float* W3  = (const float*)d_in[11];
    const float* b3  = (const float*)d_in[12];

    char* ws = (char*)d_ws;
    float* P       = (float*)(ws + OFF_P);
    float* T       = (float*)(ws + OFF_T);
    int*   pk      = (int*)(ws + OFF_PK);
    int*   row_off = (int*)(ws + OFF_ROWOFF);
    int*   counts  = (int*)(ws + OFF_COUNTS);
    int*   pofs    = (int*)(ws + OFF_POFS);
    int*   btot    = (int*)(ws + OFF_BTOT);
    int*   bbase   = (int*)(ws + OFF_BBASE);
    float* stats   = (float*)(ws + OFF_STATS);
    float* W1T     = (float*)(ws + OFF_W1T);
    float* W2T     = (float*)(ws + OFF_W2T);
    float* MT      = (float*)(ws + OFF_MT);
    float* C       = (float*)(ws + OFF_C);
    float* W3T     = (float*)(ws + OFF_W3T);

    hipMemsetAsync(ws + OFF_STATS, 0, 16384, stream);

    k_count<<<SB, 256, 0, stream>>>(EI, counts);
    k_prep<<<1, 1024, 0, stream>>>(W1, W2, W3, b3, W1T, W2T, MT, C, W3T);
    k_scanX<<<NB, 256, 0, stream>>>(counts, pofs, btot);
    k_scanY<<<1, 256, 0, stream>>>(btot, bbase, row_off);
    k_scatter<<<SB, 256, 0, stream>>>(EI, pofs, bbase, pk);
    k_bucket<<<NB, 256, 0, stream>>>(pk, bbase, row_off);
    k_P<<<782, 256, 0, stream>>>((const float4*)X, (const float4*)W1T, (float4*)P);

    for (int l = 0; l < 4; l++) {
        float* gs = stats + l * 1024;
        k_A<<<NN / 32, 256, 0, stream>>>((const float4*)P, pk, row_off, eps, b1, l,
                                         (float4*)T, gs);
        k_D<<<782, 256, 0, stream>>>((float4*)T,
                                     (const float4*)(W2T + (size_t)l * 1024),
                                     b2, g1, bt1, l, gs);
        if (l < 3)
            k_Fm<<<782, 256, 0, stream>>>((const float4*)T, g2, bt2, l, gs,
                                          (const float4*)MT, C, (float4*)P);
        else
            k_F3<<<3125, 256, 0, stream>>>((const float4*)T, g2, bt2, gs,
                                           (const float4*)W3T, b3, (float4*)d_out);
    }
}

// Round 7
// 474.729 us; speedup vs baseline: 2.1693x; 1.0699x over previous
//
#include <hip/hip_runtime.h>

#define NN 100000
#define NE 1600000
#define DD 128
#define HH 32
#define NB 196        // dst buckets of 512 nodes
#define SB 256        // scatter blocks
#define EPB 6250      // edges per scatter block (SB*EPB == NE)
#define BCAP 12288    // bucket capacity for LDS stage

// ---- workspace layout (bytes) ----
#define OFF_P        0UL
#define OFF_T        12800000UL
#define OFF_PK       25600000UL
#define OFF_ROWOFF   32000000UL
#define OFF_COUNTS   32400128UL
#define OFF_POFS     32600832UL
#define OFF_BTOT     32801536UL
#define OFF_BBASE    32802560UL
#define OFF_STATS    32803584UL
#define OFF_W1T      32819968UL
#define OFF_W2T      32836352UL
#define OFF_MT       32852736UL
#define OFF_C        32865024UL
#define OFF_W3T      32865536UL

// ---------- binning pass 1 ----------
__global__ void __launch_bounds__(256) k_count(const int* __restrict__ ei,
                                               int* __restrict__ counts) {
    __shared__ int c[NB];
    int t = threadIdx.x;
    if (t < NB) c[t] = 0;
    __syncthreads();
    int s = blockIdx.x * EPB;
    for (int e = s + t; e < s + EPB; e += 256)
        atomicAdd(&c[ei[NE + e] >> 9], 1);
    __syncthreads();
    if (t < NB) counts[t * SB + blockIdx.x] = c[t];
}

__global__ void __launch_bounds__(256) k_scanX(const int* __restrict__ counts,
                                               int* __restrict__ pofs,
                                               int* __restrict__ btot) {
    __shared__ int s[256];
    int t = threadIdx.x, b = blockIdx.x;
    int v = counts[b * SB + t];
    s[t] = v;
    __syncthreads();
    for (int off = 1; off < 256; off <<= 1) {
        int x = (t >= off) ? s[t - off] : 0;
        __syncthreads();
        s[t] += x;
        __syncthreads();
    }
    pofs[b * SB + t] = s[t] - v;
    if (t == 255) btot[b] = s[255];
}

__global__ void __launch_bounds__(256) k_scanY(const int* __restrict__ btot,
                                               int* __restrict__ bbase,
                                               int* __restrict__ row_off) {
    __shared__ int s[256];
    int t = threadIdx.x;
    int v = (t < NB) ? btot[t] : 0;
    s[t] = v;
    __syncthreads();
    for (int off = 1; off < 256; off <<= 1) {
        int x = (t >= off) ? s[t - off] : 0;
        __syncthreads();
        s[t] += x;
        __syncthreads();
    }
    if (t < NB) bbase[t] = s[t] - v;
    if (t == NB - 1) bbase[NB] = s[t];
    if (t == 0) row_off[NN] = NE;
}

__global__ void __launch_bounds__(256) k_scatter(const int* __restrict__ ei,
                                                 const int* __restrict__ pofs,
                                                 const int* __restrict__ bbase,
                                                 int* __restrict__ pk) {
    __shared__ int cur[NB];
    int t = threadIdx.x, blk = blockIdx.x;
    if (t < NB) cur[t] = bbase[t] + pofs[t * SB + blk];
    __syncthreads();
    int s = blk * EPB;
    for (int e = s + t; e < s + EPB; e += 256) {
        int src = ei[e], dst = ei[NE + e];
        int b = dst >> 9;
        int pos = atomicAdd(&cur[b], 1);
        pk[pos] = (src << 9) | (dst & 511);
    }
}

__global__ void __launch_bounds__(256) k_bucket(int* pk,
                                                const int* __restrict__ bbase,
                                                int* __restrict__ row_off) {
    __shared__ int cnt[512];
    __shared__ int ts[256];
    __shared__ int stage[BCAP];
    int t = threadIdx.x, b = blockIdx.x;
    int base = bbase[b], end = bbase[b + 1];
    cnt[t] = 0; cnt[t + 256] = 0;
    __syncthreads();
    for (int e = base + t; e < end; e += 256)
        atomicAdd(&cnt[pk[e] & 511], 1);
    __syncthreads();
    int a0 = cnt[2 * t], a1 = cnt[2 * t + 1];
    int p = a0 + a1;
    ts[t] = p;
    __syncthreads();
    for (int off = 1; off < 256; off <<= 1) {
        int x = (t >= off) ? ts[t - off] : 0;
        __syncthreads();
        ts[t] += x;
        __syncthreads();
    }
    int ex = ts[t] - p;
    cnt[2 * t] = ex;
    cnt[2 * t + 1] = ex + a0;
    int n0 = b * 512 + 2 * t;
    if (n0 < NN)     row_off[n0]     = base + ex;
    if (n0 + 1 < NN) row_off[n0 + 1] = base + ex + a0;
    __syncthreads();
    for (int e = base + t; e < end; e += 256) {
        int v = pk[e];
        int pos = atomicAdd(&cnt[v & 511], 1);
        stage[pos] = v >> 9;
    }
    __syncthreads();
    int sz = end - base;
    for (int i = t; i < sz; i += 256) pk[base + i] = stage[i];
}

// ---------- weight prep: 16 blocks x 256 ----------
// blocks 0..11: MT dots (3072); 12: W1T; 13: W2T; 14: W3T; 15: C dots (96)
__global__ void __launch_bounds__(256) k_prep(const float* __restrict__ W1,
                                              const float* __restrict__ W2,
                                              const float* __restrict__ W3,
                                              const float* __restrict__ b3,
                                              float* __restrict__ W1T,
                                              float* __restrict__ W2T,
                                              float* __restrict__ MT,
                                              float* __restrict__ C,
                                              float* __restrict__ W3T) {
    int t = threadIdx.x, b = blockIdx.x;
    if (b < 12) {
        int d = b * 256 + t;                 // 0..3071
        int l = d >> 10, rem = d & 1023;
        int i = rem >> 5, j = rem & 31;
        const float* w1r = W1 + (l + 1) * HH * DD + i * DD;
        const float* w3c = W3 + l * DD * HH + j;
        float m = 0.f;
#pragma unroll 8
        for (int k = 0; k < DD; k++) m += w1r[k] * w3c[k * HH];
        MT[l * 1024 + j * 32 + i] = m;
    } else if (b == 12) {
        for (int idx = t; idx < 4096; idx += 256) {
            int jj = idx >> 7, kk = idx & 127;
            W1T[kk * 32 + jj] = W1[jj * 128 + kk];
        }
    } else if (b == 13) {
        for (int idx = t; idx < 4096; idx += 256) {
            int l = idx >> 10, rem = idx & 1023;
            int i = rem >> 5, j = rem & 31;
            W2T[l * 1024 + j * 32 + i] = W2[l * 1024 + i * 32 + j];
        }
    } else if (b == 14) {
        for (int idx = t; idx < 4096; idx += 256) {
            int jj = idx >> 5, kk = idx & 31;
            W3T[kk * 128 + jj] = W3[3 * 4096 + jj * 32 + kk];
        }
    } else {
        if (t < 96) {
            int l = t >> 5, ii = t & 31;
            const float* w1r = W1 + (l + 1) * HH * DD + ii * DD;
            const float* bb = b3 + l * DD;
            float c = 0.f;
#pragma unroll 8
            for (int k = 0; k < DD; k++) c += w1r[k] * bb[k];
            C[l * 32 + ii] = c;
        }
    }
}

// ---------- P = X @ W1[0]^T : register-blocked, 128 nodes/block, grid 782 ----------
__global__ void __launch_bounds__(256) k_P(const float4* __restrict__ X4,
                                           const float4* __restrict__ W1T4,
                                           float4* __restrict__ P4) {
    __shared__ float xs[128 * 33];
    int t = threadIdx.x, blk = blockIdx.x;
    int i = t & 7, g = t >> 3;
    int nbase = blk * 128;
    float4 acc[4];
#pragma unroll
    for (int j = 0; j < 4; j++) acc[j] = make_float4(0.f, 0.f, 0.f, 0.f);
    for (int kt = 0; kt < 4; kt++) {
        __syncthreads();
#pragma unroll
        for (int q = 0; q < 4; q++) {
            int idx = t + 256 * q;
            int nd = idx >> 3, c4 = idx & 7;
            int node = nbase + nd;
            if (node > NN - 1) node = NN - 1;
            float4 v = X4[(size_t)node * 32 + kt * 8 + c4];
            float* dst = xs + nd * 33 + 4 * c4;
            dst[0] = v.x; dst[1] = v.y; dst[2] = v.z; dst[3] = v.w;
        }
        __syncthreads();
        const float4* Wk = W1T4 + (size_t)(kt * 32) * 8 + i;
        const float* xr0 = xs + (g * 4) * 33;
#pragma unroll
        for (int k = 0; k < 32; k++) {
            float4 w = Wk[k * 8];
            float x0 = xr0[k], x1 = xr0[33 + k], x2 = xr0[66 + k], x3 = xr0[99 + k];
            acc[0].x += x0 * w.x; acc[0].y += x0 * w.y; acc[0].z += x0 * w.z; acc[0].w += x0 * w.w;
            acc[1].x += x1 * w.x; acc[1].y += x1 * w.y; acc[1].z += x1 * w.z; acc[1].w += x1 * w.w;
            acc[2].x += x2 * w.x; acc[2].y += x2 * w.y; acc[2].z += x2 * w.z; acc[2].w += x2 * w.w;
            acc[3].x += x3 * w.x; acc[3].y += x3 * w.y; acc[3].z += x3 * w.z; acc[3].w += x3 * w.w;
        }
    }
    int node = nbase + g * 4;
#pragma unroll
    for (int j = 0; j < 4; j++)
        if (node + j < NN) P4[(size_t)(node + j) * 8 + i] = acc[j];
}

// ---------- aggregate + t1; BN1 stats (8-way replicated) ----------
__global__ void __launch_bounds__(256) k_A(const float4* __restrict__ P4,
                                           const int* __restrict__ csr,
                                           const int* __restrict__ row_off,
                                           const float* __restrict__ eps,
                                           const float* __restrict__ b1, int l,
                                           float4* __restrict__ T4,
                                           float* __restrict__ gs) {
    __shared__ float ls[64];
    int t = threadIdx.x;
    if (t < 64) ls[t] = 0.f;
    __syncthreads();
    int g = t >> 3, i = t & 7;
    int n = blockIdx.x * 32 + g;
    float e1 = 1.f + eps[l];
    int e0 = row_off[n], eend = row_off[n + 1];
    float4 p = P4[(size_t)n * 8 + i];
    float4 acc;
    acc.x = e1 * p.x; acc.y = e1 * p.y; acc.z = e1 * p.z; acc.w = e1 * p.w;
    int e = e0;
    for (; e + 4 <= eend; e += 4) {
        int s0 = csr[e], s1 = csr[e + 1], s2 = csr[e + 2], s3 = csr[e + 3];
        float4 q0 = P4[(size_t)s0 * 8 + i];
        float4 q1 = P4[(size_t)s1 * 8 + i];
        float4 q2 = P4[(size_t)s2 * 8 + i];
        float4 q3 = P4[(size_t)s3 * 8 + i];
        acc.x += (q0.x + q1.x) + (q2.x + q3.x);
        acc.y += (q0.y + q1.y) + (q2.y + q3.y);
        acc.z += (q0.z + q1.z) + (q2.z + q3.z);
        acc.w += (q0.w + q1.w) + (q2.w + q3.w);
    }
    for (; e < eend; e++) {
        int s = csr[e];
        float4 q = P4[(size_t)s * 8 + i];
        acc.x += q.x; acc.y += q.y; acc.z += q.z; acc.w += q.w;
    }
    float4 bb = ((const float4*)(b1 + l * 32))[i];
    acc.x += bb.x; acc.y += bb.y; acc.z += bb.z; acc.w += bb.w;
    T4[(size_t)n * 8 + i] = acc;
    float sx = acc.x, sy = acc.y, sz = acc.z, sw = acc.w;
    float qx = acc.x * acc.x, qy = acc.y * acc.y, qz = acc.z * acc.z, qw = acc.w * acc.w;
#pragma unroll
    for (int off = 8; off < 64; off <<= 1) {
        sx += __shfl_xor(sx, off); sy += __shfl_xor(sy, off);
        sz += __shfl_xor(sz, off); sw += __shfl_xor(sw, off);
        qx += __shfl_xor(qx, off); qy += __shfl_xor(qy, off);
        qz += __shfl_xor(qz, off); qw += __shfl_xor(qw, off);
    }
    if ((t & 56) == 0) {
        atomicAdd(&ls[4 * i + 0], sx); atomicAdd(&ls[4 * i + 1], sy);
        atomicAdd(&ls[4 * i + 2], sz); atomicAdd(&ls[4 * i + 3], sw);
        atomicAdd(&ls[32 + 4 * i + 0], qx); atomicAdd(&ls[32 + 4 * i + 1], qy);
        atomicAdd(&ls[32 + 4 * i + 2], qz); atomicAdd(&ls[32 + 4 * i + 3], qw);
    }
    __syncthreads();
    if (t < 64) atomicAdd(&gs[(blockIdx.x & 7) * 64 + t], ls[t]);
}

// ---------- t2 = relu(bn1(t1)) @ W2^T + b2; BN2 stats. 128 nodes/block, grid 782 ----------
__global__ void __launch_bounds__(256) k_D(float4* __restrict__ T4,
                                           const float4* __restrict__ W2T4,
                                           const float* __restrict__ b2,
                                           const float* __restrict__ g1,
                                           const float* __restrict__ bt1, int l,
                                           float* __restrict__ gs) {
    __shared__ float sc[32], sh[32], ls[64], a1s[128 * 33];
    int t = threadIdx.x, blk = blockIdx.x;
    if (t < 32) {
        float s0 = 0.f, s1 = 0.f;
#pragma unroll
        for (int r = 0; r < 8; r++) { s0 += gs[r * 64 + t]; s1 += gs[r * 64 + 32 + t]; }
        float m = s0 * (1.f / NN);
        float var = s1 * (1.f / NN) - m * m;
        float s = g1[l * 32 + t] * rsqrtf(var + 1e-5f);
        sc[t] = s; sh[t] = bt1[l * 32 + t] - m * s;
    } else if (t >= 64 && t < 128) {
        ls[t - 64] = 0.f;
    }
    __syncthreads();
    int nbase = blk * 128;
#pragma unroll
    for (int q = 0; q < 4; q++) {
        int idx = t + 256 * q;
        int nd = idx >> 3, c4 = idx & 7;
        int node = nbase + nd;
        if (node > NN - 1) node = NN - 1;
        float4 x = T4[(size_t)node * 8 + c4];
        float* dst = a1s + nd * 33 + 4 * c4;
        dst[0] = fmaxf(x.x * sc[4 * c4 + 0] + sh[4 * c4 + 0], 0.f);
        dst[1] = fmaxf(x.y * sc[4 * c4 + 1] + sh[4 * c4 + 1], 0.f);
        dst[2] = fmaxf(x.z * sc[4 * c4 + 2] + sh[4 * c4 + 2], 0.f);
        dst[3] = fmaxf(x.w * sc[4 * c4 + 3] + sh[4 * c4 + 3], 0.f);
    }
    __syncthreads();
    int i = t & 7, g = t >> 3;
    const float4* b24 = (const float4*)(b2 + l * 32);
    float4 b = b24[i];
    float4 acc[4];
#pragma unroll
    for (int j = 0; j < 4; j++) acc[j] = b;
    const float* xr0 = a1s + (g * 4) * 33;
#pragma unroll
    for (int k = 0; k < 32; k++) {
        float4 w = W2T4[k * 8 + i];
        float x0 = xr0[k], x1 = xr0[33 + k], x2 = xr0[66 + k], x3 = xr0[99 + k];
        acc[0].x += x0 * w.x; acc[0].y += x0 * w.y; acc[0].z += x0 * w.z; acc[0].w += x0 * w.w;
        acc[1].x += x1 * w.x; acc[1].y += x1 * w.y; acc[1].z += x1 * w.z; acc[1].w += x1 * w.w;
        acc[2].x += x2 * w.x; acc[2].y += x2 * w.y; acc[2].z += x2 * w.z; acc[2].w += x2 * w.w;
        acc[3].x += x3 * w.x; acc[3].y += x3 * w.y; acc[3].z += x3 * w.z; acc[3].w += x3 * w.w;
    }
    int node = nbase + g * 4;
    float sx = 0.f, sy = 0.f, sz = 0.f, sw = 0.f;
    float qx = 0.f, qy = 0.f, qz = 0.f, qw = 0.f;
#pragma unroll
    for (int j = 0; j < 4; j++) {
        if (node + j < NN) {
            T4[(size_t)(node + j) * 8 + i] = acc[j];
            sx += acc[j].x; sy += acc[j].y; sz += acc[j].z; sw += acc[j].w;
            qx += acc[j].x * acc[j].x; qy += acc[j].y * acc[j].y;
            qz += acc[j].z * acc[j].z; qw += acc[j].w * acc[j].w;
        }
    }
#pragma unroll
    for (int off = 8; off < 64; off <<= 1) {
        sx += __shfl_xor(sx, off); sy += __shfl_xor(sy, off);
        sz += __shfl_xor(sz, off); sw += __shfl_xor(sw, off);
        qx += __shfl_xor(qx, off); qy += __shfl_xor(qy, off);
        qz += __shfl_xor(qz, off); qw += __shfl_xor(qw, off);
    }
    if ((t & 56) == 0) {
        atomicAdd(&ls[4 * i + 0], sx); atomicAdd(&ls[4 * i + 1], sy);
        atomicAdd(&ls[4 * i + 2], sz); atomicAdd(&ls[4 * i + 3], sw);
        atomicAdd(&ls[32 + 4 * i + 0], qx); atomicAdd(&ls[32 + 4 * i + 1], qy);
        atomicAdd(&ls[32 + 4 * i + 2], qz); atomicAdd(&ls[32 + 4 * i + 3], qw);
    }
    __syncthreads();
    if (t < 64) atomicAdd(&gs[512 + (blk & 7) * 64 + t], ls[t]);
}

// ---------- l<3: P = M·relu(bn2(t2)) + c. 128 nodes/block, grid 782 ----------
__global__ void __launch_bounds__(256) k_Fm(const float4* __restrict__ T4,
                                            const float* __restrict__ g2,
                                            const float* __restrict__ bt2, int l,
                                            const float* __restrict__ gs,
                                            const float4* __restrict__ MT4,
                                            const float* __restrict__ C,
                                            float4* __restrict__ P4) {
    __shared__ float sc[32], sh[32], a2s[128 * 33];
    int t = threadIdx.x, blk = blockIdx.x;
    if (t < 32) {
        float s0 = 0.f, s1 = 0.f;
#pragma unroll
        for (int r = 0; r < 8; r++) { s0 += gs[512 + r * 64 + t]; s1 += gs[512 + r * 64 + 32 + t]; }
        float m = s0 * (1.f / NN);
        float var = s1 * (1.f / NN) - m * m;
        float s = g2[l * 32 + t] * rsqrtf(var + 1e-5f);
        sc[t] = s; sh[t] = bt2[l * 32 + t] - m * s;
    }
    __syncthreads();
    int nbase = blk * 128;
#pragma unroll
    for (int q = 0; q < 4; q++) {
        int idx = t + 256 * q;
        int nd = idx >> 3, c4 = idx & 7;
        int node = nbase + nd;
        if (node > NN - 1) node = NN - 1;
        float4 x = T4[(size_t)node * 8 + c4];
        float* dst = a2s + nd * 33 + 4 * c4;
        dst[0] = fmaxf(x.x * sc[4 * c4 + 0] + sh[4 * c4 + 0], 0.f);
        dst[1] = fmaxf(x.y * sc[4 * c4 + 1] + sh[4 * c4 + 1], 0.f);
        dst[2] = fmaxf(x.z * sc[4 * c4 + 2] + sh[4 * c4 + 2], 0.f);
        dst[3] = fmaxf(x.w * sc[4 * c4 + 3] + sh[4 * c4 + 3], 0.f);
    }
    __syncthreads();
    int i = t & 7, g = t >> 3;
    const float4* C4 = (const float4*)(C + l * 32);
    float4 c0 = C4[i];
    float4 acc[4];
#pragma unroll
    for (int j = 0; j < 4; j++) acc[j] = c0;
    const float* xr0 = a2s + (g * 4) * 33;
    const float4* Mt = MT4 + l * 256;
#pragma unroll
    for (int k = 0; k < 32; k++) {
        float4 w = Mt[k * 8 + i];
        float x0 = xr0[k], x1 = xr0[33 + k], x2 = xr0[66 + k], x3 = xr0[99 + k];
        acc[0].x += x0 * w.x; acc[0].y += x0 * w.y; acc[0].z += x0 * w.z; acc[0].w += x0 * w.w;
        acc[1].x += x1 * w.x; acc[1].y += x1 * w.y; acc[1].z += x1 * w.z; acc[1].w += x1 * w.w;
        acc[2].x += x2 * w.x; acc[2].y += x2 * w.y; acc[2].z += x2 * w.z; acc[2].w += x2 * w.w;
        acc[3].x += x3 * w.x; acc[3].y += x3 * w.y; acc[3].z += x3 * w.z; acc[3].w += x3 * w.w;
    }
    int node = nbase + g * 4;
#pragma unroll
    for (int j = 0; j < 4; j++)
        if (node + j < NN) P4[(size_t)(node + j) * 8 + i] = acc[j];
}

// ---------- l==3: out = W3·relu(bn2(t2)) + b3. 32 nodes/block, grid 3125 ----------
__global__ void __launch_bounds__(256) k_F3(const float4* __restrict__ T4,
                                            const float* __restrict__ g2,
                                            const float* __restrict__ bt2,
                                            const float* __restrict__ gs,
                                            const float4* __restrict__ W3T4,
                                            const float* __restrict__ b3,
                                            float4* __restrict__ out4) {
    __shared__ float sc[32], sh[32], a2s[32 * 33];
    int t = threadIdx.x, blk = blockIdx.x;
    if (t < 32) {
        float s0 = 0.f, s1 = 0.f;
#pragma unroll
        for (int r = 0; r < 8; r++) { s0 += gs[512 + r * 64 + t]; s1 += gs[512 + r * 64 + 32 + t]; }
        float m = s0 * (1.f / NN);
        float var = s1 * (1.f / NN) - m * m;
        float s = g2[3 * 32 + t] * rsqrtf(var + 1e-5f);
        sc[t] = s; sh[t] = bt2[3 * 32 + t] - m * s;
    }
    __syncthreads();
    {
        int nd = t >> 3, c4 = t & 7;
        float4 x = T4[(size_t)(blk * 32 + nd) * 8 + c4];
        float* dst = a2s + nd * 33 + 4 * c4;
        dst[0] = fmaxf(x.x * sc[4 * c4 + 0] + sh[4 * c4 + 0], 0.f);
        dst[1] = fmaxf(x.y * sc[4 * c4 + 1] + sh[4 * c4 + 1], 0.f);
        dst[2] = fmaxf(x.z * sc[4 * c4 + 2] + sh[4 * c4 + 2], 0.f);
        dst[3] = fmaxf(x.w * sc[4 * c4 + 3] + sh[4 * c4 + 3], 0.f);
    }
    __syncthreads();
    int j = t & 31, g = t >> 5;
    const float4* b34 = (const float4*)(b3 + 3 * 128);
    float4 b = b34[j];
    float4 acc[4];
#pragma unroll
    for (int jj = 0; jj < 4; jj++) acc[jj] = b;
    const float* xr0 = a2s + (g * 4) * 33;
#pragma unroll
    for (int k = 0; k < 32; k++) {
        float4 w = W3T4[k * 32 + j];
        float x0 = xr0[k], x1 = xr0[33 + k], x2 = xr0[66 + k], x3 = xr0[99 + k];
        acc[0].x += x0 * w.x; acc[0].y += x0 * w.y; acc[0].z += x0 * w.z; acc[0].w += x0 * w.w;
        acc[1].x += x1 * w.x; acc[1].y += x1 * w.y; acc[1].z += x1 * w.z; acc[1].w += x1 * w.w;
        acc[2].x += x2 * w.x; acc[2].y += x2 * w.y; acc[2].z += x2 * w.z; acc[2].w += x2 * w.w;
        acc[3].x += x3 * w.x; acc[3].y += x3 * w.y; acc[3].z += x3 * w.z; acc[3].w += x3 * w.w;
    }
    size_t node = (size_t)blk * 32 + g * 4;
#pragma unroll
    for (int jj = 0; jj < 4; jj++)
        out4[(node + jj) * 32 + j] = acc[jj];
}

extern "C" void kernel_launch(void* const* d_in, const int* in_sizes, int n_in,
                              void* d_out, int out_size, void* d_ws, size_t ws_size,
                              hipStream_t stream) {
    const float* X   = (const float*)d_in[0];
    const int*   EI  = (const int*)d_in[1];
    const float* eps = (const float*)d_in[2];
    const float* W1  = (const float*)d_in[3];
    const float* b1  = (const float*)d_in[4];
    const float* g1  = (const float*)d_in[5];
    const float* bt1 = (const float*)d_in[6];
    const float* W2  = (const float*)d_in[7];
    const float* b2  = (const float*)d_in[8];
    const float* g2  = (const float*)d_in[9];
    const float* bt2 = (const float*)d_in[10];
    const float* W3  = (const float*)d_in[11];
    const float* b3  = (const float*)d_in[12];

    char* ws = (char*)d_ws;
    float* P       = (float*)(ws + OFF_P);
    float* T       = (float*)(ws + OFF_T);
    int*   pk      = (int*)(ws + OFF_PK);
    int*   row_off = (int*)(ws + OFF_ROWOFF);
    int*   counts  = (int*)(ws + OFF_COUNTS);
    int*   pofs    = (int*)(ws + OFF_POFS);
    int*   btot    = (int*)(ws + OFF_BTOT);
    int*   bbase   = (int*)(ws + OFF_BBASE);
    float* stats   = (float*)(ws + OFF_STATS);
    float* W1T     = (float*)(ws + OFF_W1T);
    float* W2T     = (float*)(ws + OFF_W2T);
    float* MT      = (float*)(ws + OFF_MT);
    float* C       = (float*)(ws + OFF_C);
    float* W3T     = (float*)(ws + OFF_W3T);

    hipMemsetAsync(ws + OFF_STATS, 0, 16384, stream);

    k_count<<<SB, 256, 0, stream>>>(EI, counts);
    k_prep<<<16, 256, 0, stream>>>(W1, W2, W3, b3, W1T, W2T, MT, C, W3T);
    k_scanX<<<NB, 256, 0, stream>>>(counts, pofs, btot);
    k_scanY<<<1, 256, 0, stream>>>(btot, bbase, row_off);
    k_scatter<<<SB, 256, 0, stream>>>(EI, pofs, bbase, pk);
    k_bucket<<<NB, 256, 0, stream>>>(pk, bbase, row_off);
    k_P<<<782, 256, 0, stream>>>((const float4*)X, (const float4*)W1T, (float4*)P);

    for (int l = 0; l < 4; l++) {
        float* gs = stats + l * 1024;
        k_A<<<NN / 32, 256, 0, stream>>>((const float4*)P, pk, row_off, eps, b1, l,
                                         (float4*)T, gs);
        k_D<<<782, 256, 0, stream>>>((float4*)T,
                                     (const float4*)(W2T + (size_t)l * 1024),
                                     b2, g1, bt1, l, gs);
        if (l < 3)
            k_Fm<<<782, 256, 0, stream>>>((const float4*)T, g2, bt2, l, gs,
                                          (const float4*)MT, C, (float4*)P);
        else
            k_F3<<<3125, 256, 0, stream>>>((const float4*)T, g2, bt2, gs,
                                           (const float4*)W3T, b3, (float4*)d_out);
    }
}